// Round 10
// baseline (351.265 us; speedup 1.0000x reference)
//
#include <hip/hip_runtime.h>
#include <math.h>

// B=4, T=2048, C=1024, H=16, N=64, Q=256, nc=8, BT=8192
#define BB 4
#define TT 2048
#define CC 1024
#define HH 16
#define NN 64
#define QQ 256
#define NCH 8
#define BT 8192

typedef unsigned short u16;
typedef __attribute__((ext_vector_type(8))) short bf16x8;
typedef __attribute__((ext_vector_type(4))) short bf16x4;
typedef __attribute__((ext_vector_type(4))) float f32x4;
typedef __attribute__((ext_vector_type(4))) u16 u16x4;

// f32 -> bf16 bits, round-to-nearest-even
__device__ inline u16 f2b(float x) {
  union { float f; unsigned u; } v;
  v.f = x;
  unsigned r = v.u + 0x7FFFu + ((v.u >> 16) & 1u);
  return (u16)(r >> 16);
}
__device__ inline float b2f(u16 u) {
  union { unsigned u; float f; } v;
  v.u = ((unsigned)u) << 16;
  return v.f;
}
// 16B fragment from padded LDS row via two 8B loads (conflict-friendly)
__device__ inline bf16x8 ldfrag(const u16* p) {
  bf16x4 lo = *(const bf16x4*)p;
  bf16x4 hi = *(const bf16x4*)(p + 4);
  return __builtin_shufflevector(lo, hi, 0, 1, 2, 3, 4, 5, 6, 7);
}
// stage 64x64 bf16 tile (global pitch `pitch` u16) into LDS stride-72
__device__ inline void stage_tile(const u16* __restrict__ g, size_t base,
                                  int pitch, int tid, u16* __restrict__ lds) {
#pragma unroll
  for (int it = 0; it < 2; it++) {
    int cidx = tid + it * 256;  // 0..511
    int r = cidx >> 3, c8 = (cidx & 7) * 8;
    bf16x8 v = *(const bf16x8*)(g + base + (size_t)r * pitch + c8);
    *(bf16x4*)(lds + r * 72 + c8) = __builtin_shufflevector(v, v, 0, 1, 2, 3);
    *(bf16x4*)(lds + r * 72 + c8 + 4) = __builtin_shufflevector(v, v, 4, 5, 6, 7);
  }
}

// ---------------------------------------------------------------------------
// 1. time-shift mix: xxx -> bf16 only (xx recomputed inline in blend)
// ---------------------------------------------------------------------------
__global__ __launch_bounds__(256) void mix_kernel(const float* __restrict__ x,
                                                  const float* __restrict__ tmx,
                                                  u16* __restrict__ xxxb) {
  size_t e = ((size_t)blockIdx.x * 256 + threadIdx.x) * 4;
  int c = (int)(e & 1023);
  size_t row = e >> 10;
  int t = (int)(row & 2047);
  float4 xv = *(const float4*)(x + e);
  float4 pv = make_float4(0.f, 0.f, 0.f, 0.f);
  if (t > 0) pv = *(const float4*)(x + e - 1024);
  float4 d = make_float4(pv.x - xv.x, pv.y - xv.y, pv.z - xv.z, pv.w - xv.w);
  u16x4 o;
  o.x = f2b(xv.x + d.x * tmx[c + 0]);
  o.y = f2b(xv.y + d.y * tmx[c + 1]);
  o.z = f2b(xv.z + d.z * tmx[c + 2]);
  o.w = f2b(xv.w + d.w * tmx[c + 3]);
  *(u16x4*)(xxxb + e) = o;
}

// ---------------------------------------------------------------------------
// merged weight prep (ONE launch), grid (16,16,8):
//   z<4 : big 1024x1024 weight f32[k][n] -> bf16 Wt[n][k]
//   z=4 : maa_w1 f32[1024][128] -> w1T bf16[128][1024]
//   z=5 : maa_w2 f32[128][1024] -> w2T bf16[1024][128]
//   z=6 : decay_w1 f32[1024][64] -> d1T bf16[64][1024]
//   z=7 : dw2r reduce (blocks x<4, y==0 only)
// out-of-range tiles return immediately.
// ---------------------------------------------------------------------------
__global__ __launch_bounds__(256) void cvt_all(
    const float* __restrict__ W0, const float* __restrict__ W1,
    const float* __restrict__ W2, const float* __restrict__ W3,
    u16* __restrict__ O0, u16* __restrict__ O1, u16* __restrict__ O2,
    u16* __restrict__ O3, const float* __restrict__ w1,
    const float* __restrict__ w2, const float* __restrict__ d1,
    u16* __restrict__ o1, u16* __restrict__ o2, u16* __restrict__ o3,
    const float* __restrict__ dw2, const float* __restrict__ td,
    float* __restrict__ dw2r, float* __restrict__ tdr,
    u16* __restrict__ dw2rbT) {
  int z = blockIdx.z;
  if (z == 7) {
    if (blockIdx.y != 0 || blockIdx.x >= 4) return;
    int idx = blockIdx.x * 256 + threadIdx.x;
    if (idx < 1024) {
      int j = idx >> 4, h = idx & 15;
      float s = 0.f;
      for (int n = 0; n < 64; n++) s += dw2[(size_t)j * 1024 + h * 64 + n];
      float m = s * (1.f / 64.f);
      dw2r[j * 16 + h] = m;
      dw2rbT[h * 64 + j] = f2b(m);
    }
    if (idx < 16) {
      float s = 0.f;
      for (int n = 0; n < 64; n++) s += td[idx * 64 + n];
      tdr[idx] = s * (1.f / 64.f);
    }
    return;
  }
  const float* in;
  u16* out;
  int R, C;
  switch (z) {
    case 0: in = W0; out = O0; R = 1024; C = 1024; break;
    case 1: in = W1; out = O1; R = 1024; C = 1024; break;
    case 2: in = W2; out = O2; R = 1024; C = 1024; break;
    case 3: in = W3; out = O3; R = 1024; C = 1024; break;
    case 4: in = w1; out = o1; R = 1024; C = 128; break;
    case 5: in = w2; out = o2; R = 128; C = 1024; break;
    default: in = d1; out = o3; R = 1024; C = 64; break;
  }
  int c0 = blockIdx.x * 64, r0 = blockIdx.y * 64;
  if (c0 >= C || r0 >= R) return;
  __shared__ float t[64][65];
#pragma unroll
  for (int it = 0; it < 16; it++) {
    int idx = it * 256 + threadIdx.x;
    int r = idx >> 6, c = idx & 63;
    t[r][c] = in[(size_t)(r0 + r) * C + c0 + c];
  }
  __syncthreads();
#pragma unroll
  for (int it = 0; it < 16; it++) {
    int idx = it * 256 + threadIdx.x;
    int c = idx >> 6, r = idx & 63;
    out[(size_t)(c0 + c) * R + r0 + r] = f2b(t[r][c]);
  }
}

// ---------------------------------------------------------------------------
// maa GEMM: mb = tanh(xxx @ w1) : A[8192][1024] x w1T[128][1024] -> [8192][128]
// 64x64 tiles -> grid (2,128) = 256 blocks (full-CU coverage).
// ---------------------------------------------------------------------------
__global__ __launch_bounds__(256) void gemm_maa(const u16* __restrict__ A,
                                                const u16* __restrict__ Bt,
                                                u16* __restrict__ Cb) {
  __shared__ u16 As[64 * 32];
  __shared__ u16 Bs[64 * 32];
  const int tid = threadIdx.x;
  const int lane = tid & 63;
  const int wave = tid >> 6;
  const int wc = wave * 16;
  const int fr = lane & 15;
  const int fq = lane >> 4;
  const int row0 = blockIdx.y * 64;
  const int col0 = blockIdx.x * 64;

  f32x4 acc[4];
#pragma unroll
  for (int i = 0; i < 4; i++) acc[i] = (f32x4){0.f, 0.f, 0.f, 0.f};

  const int ra = tid >> 2, ca = (tid & 3) * 8;

  for (int k0 = 0; k0 < 1024; k0 += 32) {
    __builtin_amdgcn_global_load_lds(
        (const __attribute__((address_space(1))) void*)(A + (size_t)(row0 + ra) * 1024 + k0 + ca),
        (__attribute__((address_space(3))) void*)(As + tid * 8), 16, 0, 0);
    __builtin_amdgcn_global_load_lds(
        (const __attribute__((address_space(1))) void*)(Bt + (size_t)(col0 + ra) * 1024 + k0 + ca),
        (__attribute__((address_space(3))) void*)(Bs + tid * 8), 16, 0, 0);
    __syncthreads();
    bf16x8 bf = *(const bf16x8*)(Bs + ((wc + fr) * 32 + fq * 8));
#pragma unroll
    for (int i = 0; i < 4; i++) {
      bf16x8 af = *(const bf16x8*)(As + ((i * 16 + fr) * 32 + fq * 8));
      acc[i] = __builtin_amdgcn_mfma_f32_16x16x32_bf16(af, bf, acc[i], 0, 0, 0);
    }
    __syncthreads();
  }
#pragma unroll
  for (int i = 0; i < 4; i++) {
    int grow = row0 + i * 16 + fq * 4;
#pragma unroll
    for (int r = 0; r < 4; r++)
      Cb[(size_t)(grow + r) * 128 + col0 + wc + fr] = f2b(tanhf(acc[i][r]));
  }
}

// ---------------------------------------------------------------------------
// Deep-pipelined bf16 GEMM v5: M=8192, N=1024, K=1024.
// BM=128 x BN=256 x **BK=32**, 512 threads (8 waves, 64x64 wave tiles).
// 3 LDS buffers now 24 KB each = 72 KB total -> **2 blocks/CU** (was 144 KB
// -> 1 block/CU). Co-resident block's MFMA hides this block's barrier/vmcnt
// stalls (m114 mechanism; m97 ran 3 blocks/CU at higher perf with MORE
// barriers/K). Depth-2 prefetch, counted vmcnt(3) (3 loads/thread/tile),
// raw s_barrier (1 per K-tile, 32 tiles), XOR chunk-swizzle adapted to
// 4-chunk rows (gch=(pos&3)^(r&3); read chunk fq^(fr&3) -- consistent
// involution since frag-row & 3 == fr & 3), bijective XCD swizzle.
// grid (4, 64, gz); nwg % 8 == 0.
// ---------------------------------------------------------------------------
#define DP_ABUF 4096    /* u16: 128*32 */
#define DP_BBUF 8192    /* u16: 256*32 */
#define DP_SBUF 12288   /* u16 per buffer (24 KB) */
#define DP_SMEM_BYTES 73728 /* 3 buffers = 72 KB */

template <bool TRIPLE, bool F32OUT>
__global__ __launch_bounds__(512, 2) void gemm_dp(
    const u16* __restrict__ A0, const u16* __restrict__ A1,
    const u16* __restrict__ A2, const u16* __restrict__ B0,
    const u16* __restrict__ B1, const u16* __restrict__ B2,
    float* __restrict__ Cf, u16* __restrict__ C0, u16* __restrict__ C1,
    u16* __restrict__ C2) {
  extern __shared__ __align__(16) u16 smem[];
  // T1: bijective XCD swizzle over flattened grid (x fastest; gridDim=(4,64,z))
  const int nwg = (int)(gridDim.x * gridDim.y * gridDim.z);
  const int wg = (int)(blockIdx.x + (blockIdx.y << 2) + (blockIdx.z << 8));
  const int cpx = nwg >> 3;
  const int swz = (wg & 7) * cpx + (wg >> 3);
  const int bx = swz & 3;
  const int by = (swz >> 2) & 63;
  const int bz = swz >> 8;

  const u16* __restrict__ A;
  const u16* __restrict__ Bt;
  u16* __restrict__ Cb;
  if (TRIPLE) {
    switch (bz) {
      case 0: A = A0; Bt = B0; Cb = C0; break;
      case 1: A = A1; Bt = B1; Cb = C1; break;
      default: A = A2; Bt = B2; Cb = C2; break;
    }
  } else {
    A = A0; Bt = B0; Cb = C0;
  }

  const int tid = threadIdx.x;
  const int lane = tid & 63;
  const int wave = tid >> 6;        // 0..7
  const int wr = (wave >> 2) * 64;  // 0 / 64
  const int wc = (wave & 3) * 64;   // 0 / 64 / 128 / 192
  const int fr = lane & 15;
  const int fq = lane >> 4;
  const int s4 = fr & 3;            // == (frag row) & 3
  const int row0 = by * 128;
  const int col0 = bx * 256;

  // per-lane LDS frag offsets (u16 units), loop-invariant; single K-slice
  int aoff[4], boff[4];
#pragma unroll
  for (int mi = 0; mi < 4; mi++)
    aoff[mi] = (wr + mi * 16 + fr) * 32 + ((fq ^ s4) * 8);
#pragma unroll
  for (int nj = 0; nj < 4; nj++)
    boff[nj] = (wc + nj * 16 + fr) * 32 + ((fq ^ s4) * 8);

  // stage tile kt (3 x 16B per thread: A 1, B 2) into buffer q; global source
  // pre-swizzled so linear LDS dest + swizzled read = consistent involution.
  auto stage = [&](int kt, int q) {
    const u16* __restrict__ gA = A + (size_t)row0 * 1024 + kt * 32;
    const u16* __restrict__ gB = Bt + (size_t)col0 * 1024 + kt * 32;
    u16* dA = smem + q * DP_SBUF;
    u16* dB = dA + DP_ABUF;
    {
      int pos = tid;                    // 0..511 (A: 128 rows x 4 chunks)
      int r = pos >> 2, gch = (pos & 3) ^ (r & 3);
      __builtin_amdgcn_global_load_lds(
          (const __attribute__((address_space(1))) void*)(gA + (size_t)r * 1024 + gch * 8),
          (__attribute__((address_space(3))) void*)(dA + pos * 8), 16, 0, 0);
    }
#pragma unroll
    for (int p = 0; p < 2; p++) {
      int pos = tid + p * 512;          // 0..1023 (B: 256 rows x 4 chunks)
      int r = pos >> 2, gch = (pos & 3) ^ (r & 3);
      __builtin_amdgcn_global_load_lds(
          (const __attribute__((address_space(1))) void*)(gB + (size_t)r * 1024 + gch * 8),
          (__attribute__((address_space(3))) void*)(dB + pos * 8), 16, 0, 0);
    }
  };

  f32x4 acc[4][4];
#pragma unroll
  for (int mi = 0; mi < 4; mi++)
#pragma unroll
    for (int nj = 0; nj < 4; nj++) acc[mi][nj] = (f32x4){0.f, 0.f, 0.f, 0.f};

  auto iter_body = [&](int qc, int qs, bool dostage, int t2) {
    if (dostage) stage(t2, qs);  // issue next+1 tile loads early
    const u16* sA = smem + qc * DP_SBUF;
    const u16* sB = sA + DP_ABUF;
    bf16x8 av[4], bv[4];
#pragma unroll
    for (int mi = 0; mi < 4; mi++) av[mi] = *(const bf16x8*)(sA + aoff[mi]);
#pragma unroll
    for (int nj = 0; nj < 4; nj++) bv[nj] = *(const bf16x8*)(sB + boff[nj]);
    __builtin_amdgcn_s_setprio(1);
#pragma unroll
    for (int mi = 0; mi < 4; mi++)
#pragma unroll
      for (int nj = 0; nj < 4; nj++)
        acc[mi][nj] = __builtin_amdgcn_mfma_f32_16x16x32_bf16(
            av[mi], bv[nj], acc[mi][nj], 0, 0, 0);
    __builtin_amdgcn_s_setprio(0);
  };

  // prologue: 2 tiles in flight (6 loads)
  stage(0, 0);
  stage(1, 1);
  int qc = 0, qs = 2;
  // main loop: wait current tile (vmcnt 3: leaves next tile's 3 in flight)
  for (int t = 0; t < 30; t++) {
    asm volatile("s_waitcnt vmcnt(3)" ::: "memory");
    __builtin_amdgcn_s_barrier();
    iter_body(qc, qs, true, t + 2);
    qc = (qc == 2) ? 0 : qc + 1;
    qs = (qs == 2) ? 0 : qs + 1;
  }
  // t = 30: no more staging; tile 31's 3 loads remain in flight
  asm volatile("s_waitcnt vmcnt(3)" ::: "memory");
  __builtin_amdgcn_s_barrier();
  iter_body(qc, 0, false, 0);
  qc = (qc == 2) ? 0 : qc + 1;
  // t = 31: drain
  asm volatile("s_waitcnt vmcnt(0)" ::: "memory");
  __builtin_amdgcn_s_barrier();
  iter_body(qc, 0, false, 0);

#pragma unroll
  for (int mi = 0; mi < 4; mi++) {
    int grow = row0 + wr + mi * 16 + fq * 4;
#pragma unroll
    for (int nj = 0; nj < 4; nj++) {
      int gcol = col0 + wc + nj * 16 + fr;
#pragma unroll
      for (int r = 0; r < 4; r++) {
        if (F32OUT)
          Cf[(size_t)(grow + r) * 1024 + gcol] = acc[mi][nj][r];
        else
          Cb[(size_t)(grow + r) * 1024 + gcol] = f2b(acc[mi][nj][r]);
      }
    }
  }
}

// ---------------------------------------------------------------------------
// 3. blend via MFMA (fused x/xx/tm* epilogue); xx recomputed inline from x.
// ---------------------------------------------------------------------------
__global__ __launch_bounds__(256) void blend_mfma(
    const u16* __restrict__ mb, const u16* __restrict__ w2T,
    const float* __restrict__ x,
    const float* __restrict__ tmw, const float* __restrict__ tmk,
    const float* __restrict__ tmv, const float* __restrict__ tmr,
    u16* __restrict__ xwb, u16* __restrict__ xkb, u16* __restrict__ xvb,
    u16* __restrict__ xrb) {
  __shared__ u16 mS[64 * 136];
  __shared__ u16 wS[64 * 136];
  const int tid = threadIdx.x;
  const int lane = tid & 63;
  const int w = tid >> 6;
  const int fr = lane & 15;
  const int fq = lane >> 4;
  const int c0 = blockIdx.x * 64;
  const int bt0 = blockIdx.y * 64;

#pragma unroll
  for (int it = 0; it < 4; it++) {
    int idx = tid + it * 256;  // 0..1023
    int r = idx >> 4, c8 = (idx & 15) * 8;
    bf16x8 v = *(const bf16x8*)(mb + (size_t)(bt0 + r) * 128 + c8);
    *(bf16x4*)(mS + r * 136 + c8) = __builtin_shufflevector(v, v, 0, 1, 2, 3);
    *(bf16x4*)(mS + r * 136 + c8 + 4) = __builtin_shufflevector(v, v, 4, 5, 6, 7);
    bf16x8 u = *(const bf16x8*)(w2T + (size_t)(c0 + r) * 128 + c8);
    *(bf16x4*)(wS + r * 136 + c8) = __builtin_shufflevector(u, u, 0, 1, 2, 3);
    *(bf16x4*)(wS + r * 136 + c8 + 4) = __builtin_shufflevector(u, u, 4, 5, 6, 7);
  }
  __syncthreads();

  f32x4 acc[4][4];  // [col-tile j][f]
#pragma unroll
  for (int j = 0; j < 4; j++)
#pragma unroll
    for (int f = 0; f < 4; f++) acc[j][f] = (f32x4){0.f, 0.f, 0.f, 0.f};

#pragma unroll
  for (int f = 0; f < 4; f++) {
    bf16x8 aA = ldfrag(mS + (w * 16 + fr) * 136 + f * 32 + fq * 8);
#pragma unroll
    for (int j = 0; j < 4; j++) {
      bf16x8 bB = ldfrag(wS + (j * 16 + fr) * 136 + f * 32 + fq * 8);
      acc[j][f] = __builtin_amdgcn_mfma_f32_16x16x32_bf16(aA, bB, acc[j][f], 0, 0, 0);
    }
  }

#pragma unroll
  for (int j = 0; j < 4; j++) {
    int c = c0 + j * 16 + fr;
    float w_ = tmw[c], k_ = tmk[c], v_ = tmv[c], r_ = tmr[c];
#pragma unroll
    for (int rr = 0; rr < 4; rr++) {
      int bt = bt0 + w * 16 + fq * 4 + rr;
      size_t g = (size_t)bt * 1024 + c;
      float xv_ = x[g];
      float xp = ((bt & 2047) != 0) ? x[g - 1024] : 0.f;
      float dx = xp - xv_;
      xwb[g] = f2b(xv_ + dx * (w_ + acc[j][0][rr]));
      xkb[g] = f2b(xv_ + dx * (k_ + acc[j][1][rr]));
      xvb[g] = f2b(xv_ + dx * (v_ + acc[j][2][rr]));
      xrb[g] = f2b(xv_ + dx * (r_ + acc[j][3][rr]));
    }
  }
}

// ---------------------------------------------------------------------------
// 5b. fused decay GEMM: h1 = tanh(xw @ d1) via MFMA (K=1024), then
//     wlog = -exp(tdr + h1 @ dw2r). 32-row tiles -> 256 blocks (full CU
//     coverage); BK=64 with gemm_dp's XOR chunk-swizzle recipe.
// ---------------------------------------------------------------------------
__global__ __launch_bounds__(256) void decay_mfma(const u16* __restrict__ xwb,
                                                  const u16* __restrict__ d1T,
                                                  const u16* __restrict__ dw2rbT,
                                                  const float* __restrict__ tdr,
                                                  float* __restrict__ wlog) {
  __shared__ u16 As[32 * 64];
  __shared__ u16 Bs[64 * 64];
  __shared__ u16 h1S[32 * 72];
  __shared__ u16 dwS[16 * 72];
  const int tid = threadIdx.x;
  const int lane = tid & 63;
  const int w = tid >> 6;
  const int fr = lane & 15;
  const int fq = lane >> 4;
  const int s8 = fr & 7;
  const int bt0 = blockIdx.x * 32;

#pragma unroll
  for (int it = 0; it < 4; it++) {
    int idx = tid + it * 256;
    int r = idx >> 6, c = idx & 63;
    dwS[r * 72 + c] = dw2rbT[r * 64 + c];
  }

  f32x4 acc[2];
#pragma unroll
  for (int mi = 0; mi < 2; mi++) acc[mi] = (f32x4){0.f, 0.f, 0.f, 0.f};

  const int raA = tid >> 3;              // 0..31
  const int gchA = (tid & 7) ^ (raA & 7);

  for (int k0 = 0; k0 < 1024; k0 += 64) {
    __builtin_amdgcn_global_load_lds(
        (const __attribute__((address_space(1))) void*)(
            xwb + (size_t)(bt0 + raA) * 1024 + k0 + gchA * 8),
        (__attribute__((address_space(3))) void*)(As + tid * 8), 16, 0, 0);
#pragma unroll
    for (int p = 0; p < 2; p++) {
      int pos = tid + p * 256;           // 0..511
      int r = pos >> 3, gch = (pos & 7) ^ (r & 7);
      __builtin_amdgcn_global_load_lds(
          (const __attribute__((address_space(1))) void*)(
              d1T + (size_t)r * 1024 + k0 + gch * 8),
          (__attribute__((address_space(3))) void*)(Bs + pos * 8), 16, 0, 0);
    }
    __syncthreads();
#pragma unroll
    for (int ks = 0; ks < 2; ks++) {
      int chunk = ((ks * 4 + fq) ^ s8) * 8;
      bf16x8 bB = *(const bf16x8*)(Bs + (w * 16 + fr) * 64 + chunk);
#pragma unroll
      for (int mi = 0; mi < 2; mi++) {
        bf16x8 aA = *(const bf16x8*)(As + (mi * 16 + fr) * 64 + chunk);
        acc[mi] = __builtin_amdgcn_mfma_f32_16x16x32_bf16(aA, bB, acc[mi], 0, 0, 0);
      }
    }
    __syncthreads();
  }
#pragma unroll
  for (int mi = 0; mi < 2; mi++)
#pragma unroll
    for (int rr = 0; rr < 4; rr++)
      h1S[(mi * 16 + fq * 4 + rr) * 72 + w * 16 + fr] = f2b(tanhf(acc[mi][rr]));
  __syncthreads();

  if (w < 2) {
    f32x4 a2 = (f32x4){0.f, 0.f, 0.f, 0.f};
#pragma unroll
    for (int ks = 0; ks < 2; ks++) {
      bf16x8 aA = ldfrag(h1S + (w * 16 + fr) * 72 + ks * 32 + fq * 8);
      bf16x8 bB = ldfrag(dwS + fr * 72 + ks * 32 + fq * 8);
      a2 = __builtin_amdgcn_mfma_f32_16x16x32_bf16(aA, bB, a2, 0, 0, 0);
    }
    float tdv = tdr[fr];
#pragma unroll
    for (int rr = 0; rr < 4; rr++) {
      int bt = bt0 + w * 16 + fq * 4 + rr;
      int b = bt >> 11, tl = bt & 2047;
      wlog[((size_t)(b * 16 + fr)) * 2048 + tl] = -__expf(tdv + a2[rr]);
    }
  }
}

// ---------------------------------------------------------------------------
// 7. per-chunk scan
// ---------------------------------------------------------------------------
__global__ __launch_bounds__(256) void wprep_kernel(const float* __restrict__ wlog,
                                                    float* __restrict__ cum,
                                                    float* __restrict__ excl,
                                                    float* __restrict__ wsl) {
  int bid = blockIdx.x;
  int c = bid & 7, bh = bid >> 3;
  int q = threadIdx.x;
  float v = wlog[(size_t)bh * 2048 + c * 256 + q];
  __shared__ float s[256];
  s[q] = v;
  float val = v;
  for (int off = 1; off < 256; off <<= 1) {
    __syncthreads();
    float t = (q >= off) ? s[q - off] : 0.f;
    __syncthreads();
    val += t;
    s[q] = val;
  }
  __syncthreads();
  float total = s[255];
  cum[(size_t)bid * 256 + q] = val;
  excl[(size_t)bid * 256 + q] = val - v;
  if (q == 0) wsl[bid] = total;
}

// ---------------------------------------------------------------------------
// kvfuse: per (bh, chunk) block — transpose k,v quarters into LDS, compute
// diag (full-wave reduce), write vT (global, for attn), and accumulate
// kv = (k*w_inter)^T @ v via MFMA in the same kernel.
// ---------------------------------------------------------------------------
__global__ __launch_bounds__(256) void kvfuse_kernel(
    const u16* __restrict__ vb, const u16* __restrict__ kb,
    const u16* __restrict__ rb, const float* __restrict__ faaaa,
    const float* __restrict__ cum, const float* __restrict__ wsl,
    u16* __restrict__ vT, float* __restrict__ diagG, float* __restrict__ kvb) {
  int bid = blockIdx.x;
  int c = bid & 7, bh = bid >> 3;
  int b = bh >> 4, h = bh & 15;
  __shared__ float tv[64][65];
  __shared__ float tk[64][65];
  __shared__ u16 kSb[64 * 72];
  __shared__ u16 vSb[64 * 72];
  __shared__ float wfacS[256];
  __shared__ float faS[64];
  const int tid = threadIdx.x;
  const int lane = tid & 63;
  const int w = tid >> 6;
  const int fr = lane & 15;
  const int fq = lane >> 4;
  const int m = lane;

  float wslog = wsl[bid];
  wfacS[tid] = __expf(wslog - cum[(size_t)bid * 256 + tid]);
  if (tid < 64) faS[tid] = faaaa[h * 64 + tid];

  f32x4 acc[4];
#pragma unroll
  for (int j = 0; j < 4; j++) acc[j] = (f32x4){0.f, 0.f, 0.f, 0.f};

  for (int qt = 0; qt < 4; qt++) {
    __syncthreads();  // tv/tk free (prev transpose done); wfacS/faS ready
    float fam = faS[m];
    int t0 = c * QQ + qt * 64;
#pragma unroll
    for (int it = 0; it < 16; it++) {
      int r = it * 4 + w;
      size_t g = ((size_t)(b * TT + t0 + r)) * CC + h * 64 + m;
      float vraw = b2f(vb[g]);
      float kraw = b2f(kb[g]);
      float rraw = b2f(rb[g]);
      tv[r][m] = vraw;
      tk[r][m] = kraw;
      float s = rraw * fam * kraw;
      s += __shfl_xor(s, 1);
      s += __shfl_xor(s, 2);
      s += __shfl_xor(s, 4);
      s += __shfl_xor(s, 8);
      s += __shfl_xor(s, 16);
      s += __shfl_xor(s, 32);
      if (m == 0) diagG[(size_t)bh * 2048 + t0 + r] = s;
    }
    __syncthreads();
#pragma unroll
    for (int it = 0; it < 16; it++) {
      int idx = it * 256 + tid;
      int mm = idx >> 6, tl = idx & 63;
      float vv = tv[tl][mm];
      float kk = tk[tl][mm] * wfacS[qt * 64 + tl];
      u16 vbv = f2b(vv);
      vT[((size_t)(bh * 64 + mm)) * TT + t0 + tl] = vbv;
      vSb[mm * 72 + tl] = vbv;
      kSb[mm * 72 + tl] = f2b(kk);
    }
    __syncthreads();
#pragma unroll
    for (int ks = 0; ks < 2; ks++) {
      bf16x8 aA = ldfrag(kSb + (w * 16 + fr) * 72 + ks * 32 + fq * 8);
#pragma unroll
      for (int j = 0; j < 4; j++) {
        bf16x8 bB = ldfrag(vSb + (j * 16 + fr) * 72 + ks * 32 + fq * 8);
        acc[j] = __builtin_amdgcn_mfma_f32_16x16x32_bf16(aA, bB, acc[j], 0, 0, 0);
      }
    }
  }
#pragma unroll
  for (int j = 0; j < 4; j++)
#pragma unroll
    for (int rr = 0; rr < 4; rr++)
      kvb[(size_t)bid * 4096 + (w * 16 + fq * 4 + rr) * 64 + j * 16 + fr] = acc[j][rr];
}

// ---------------------------------------------------------------------------
// 8b. sequential state scan over chunks — 256 blocks (bh x 4 slices), float4
// ---------------------------------------------------------------------------
__global__ __launch_bounds__(256) void scan_kernel(const float* __restrict__ kvb,
                                                   const float* __restrict__ wsl,
                                                   float* __restrict__ st) {
  int bh = blockIdx.x >> 2;
  int sl = blockIdx.x & 3;
  int tid = threadIdx.x;
  f32x4 s = (f32x4){0.f, 0.f, 0.f, 0.f};
  for (int c = 0; c < 8; c++) {
    int bid = bh * 8 + c;
    float w = __expf(wsl[bid]);
    size_t e = (size_t)bid * 4096 + sl * 1024 + tid * 4;
    f32x4 kv = *(const f32x4*)(kvb + e);
    *(f32x4*)(st + e) = s;
    s = w * s + kv;
  }
}

// ---------------------------------------------------------------------------
// 9. MFMA fused attention — qt-PAIR blocking:
// process qt in pairs {2p, 2p+1}: hold acc[2][4] + rA[2][2] in registers,
// stage rt(2p+1) into the idle pt slot, loop kti once per pair.
// Mask via factored exp tables; diag from diagG.
// ---------------------------------------------------------------------------
__global__ __launch_bounds__(256) void attn_mfma(
    const u16* __restrict__ rb, const u16* __restrict__ kb,
    const u16* __restrict__ vT, const float* __restrict__ stg,
    const float* __restrict__ cum, const float* __restrict__ excl,
    const float* __restrict__ diagG, float* __restrict__ y) {
  int bid = blockIdx.x;
  int c = bid & 7, bh = bid >> 3;
  int b = bh >> 4, h = bh & 15;
  __shared__ u16 rt[64 * 72];
  __shared__ u16 kt[64 * 72];
  __shared__ u16 vt[64 * 72];
  __shared__ u16 pt[64 * 72];
  __shared__ u16 stT[64 * 72];
  __shared__ float cumS[256], exS[256], diagS[256], ekS[256];

  const int tid = threadIdx.x;
  const int lane = tid & 63;
  const int w = tid >> 6;
  const int fr = lane & 15;
  const int fq = lane >> 4;

  cumS[tid] = cum[(size_t)bid * 256 + tid];
  exS[tid] = excl[(size_t)bid * 256 + tid];
  diagS[tid] = diagG[(size_t)bh * 2048 + c * 256 + tid];
#pragma unroll
  for (int it = 0; it < 16; it++) {
    int idx = tid + it * 256;
    int n = idx >> 6, mm = idx & 63;
    stT[mm * 72 + n] = f2b(stg[(size_t)bid * 4096 + idx]);
  }
  __syncthreads();
  const float ccm = cumS[127];
  ekS[tid] = __expf(ccm - cumS[tid]);

  const size_t rowbase = ((size_t)b * TT + c * QQ) * CC + h * 64;
  const size_t vbase0 = (size_t)bh * 64 * TT + c * QQ;
  const int ql0 = w * 16 + fq * 4;

#pragma unroll
  for (int p = 0; p < 2; p++) {
    __syncthreads();  // prev pair's pt/kt/vt reads complete (p=1); noop-safe p=0
    stage_tile(rb, rowbase + (size_t)((2 * p) * 64) * CC, CC, tid, rt);
    stage_tile(rb, rowbase + (size_t)((2 * p + 1) * 64) * CC, CC, tid, pt);
    __syncthreads();
    bf16x8 rA[2][2];
    rA[0][0] = ldfrag(rt + (w * 16 + fr) * 72 + fq * 8);
    rA[0][1] = ldfrag(rt + (w * 16 + fr) * 72 + 32 + fq * 8);
    rA[1][0] = ldfrag(pt + (w * 16 + fr) * 72 + fq * 8);
    rA[1][1] = ldfrag(pt + (w * 16 + fr) * 72 + 32 + fq * 8);

    f32x4 acc[2][4];
    float eqc[2][4];
#pragma unroll
    for (int j = 0; j < 2; j++) {
      int qt = 2 * p + j;
#pragma unroll
      for (int jm = 0; jm < 4; jm++) acc[j][jm] = (f32x4){0.f, 0.f, 0.f, 0.f};
#pragma unroll
      for (int ks = 0; ks < 2; ks++)
#pragma unroll
        for (int jm = 0; jm < 4; jm++) {
          bf16x8 bB = ldfrag(stT + (jm * 16 + fr) * 72 + ks * 32 + fq * 8);
          acc[j][jm] = __builtin_amdgcn_mfma_f32_16x16x32_bf16(
              rA[j][ks], bB, acc[j][jm], 0, 0, 0);
        }
      float er[4];
#pragma unroll
      for (int rr = 0; rr < 4; rr++) {
        float ex = exS[qt * 64 + ql0 + rr];
        er[rr] = __expf(ex);
        eqc[j][rr] = __expf(ex - ccm);
      }
#pragma unroll
      for (int jm = 0; jm < 4; jm++)
#pragma unroll
        for (int rr = 0; rr < 4; rr++) acc[j][jm][rr] *= er[rr];
    }

#pragma unroll
    for (int kti = 0; kti < 2 * p + 2; kti++) {
      __syncthreads();  // rA[1] frag reads (kti=0) / prev PV pt reads done
      stage_tile(kb, rowbase + (size_t)(kti * 64) * CC, CC, tid, kt);
      stage_tile(vT, vbase0 + (size_t)(kti * 64), TT, tid, vt);
      __syncthreads();
#pragma unroll
      for (int j = 0; j < 2; j++) {
        int qt = 2 * p + j;
        if (kti > qt) continue;  // compile-time resolved (all loops unrolled)
        f32x4 sacc[4];
#pragma unroll
        for (int jj = 0; jj < 4; jj++) sacc[jj] = (f32x4){0.f, 0.f, 0.f, 0.f};
#pragma unroll
        for (int ks = 0; ks < 2; ks++)
#pragma unroll
          for (int jj = 0; jj < 4; jj++) {
            bf16x8 bB = ldfrag(kt + (jj * 16 + fr) * 72 + ks * 32 + fq * 8);
            sacc[jj] = __builtin_amdgcn_mfma_f32_16x16x32_bf16(
                rA[j][ks], bB, sacc[jj], 0, 0, 0);
          }
#pragma unroll
        for (int jj = 0; jj < 4; jj++) {
          int kcol = kti * 64 + jj * 16 + fr;
          float ek = ekS[kcol];
#pragma unroll
          for (int rr = 0; rr < 4; rr++) {
            int qrow = qt * 64 + ql0 + rr;
            float vsc;
            if (kcol < qrow)
              vsc = sacc[jj][rr] * eqc[j][rr] * ek;
            else if (kcol == qrow)
              vsc = diagS[qrow];
            else
              vsc = 0.f;
            pt[(ql0 + rr) * 72 + jj * 16 + fr] = f2b(vsc);
          }
        }
        __syncthreads();
#pragma unroll
        for (int ks = 0; ks < 2; ks++) {
          bf16x8 pA = ldfrag(pt + (w * 16 + fr) * 72 + ks * 32 + fq * 8);
#pragma unroll
          for (int jm = 0; jm < 4; jm++) {
            bf16x8 vB = ldfrag(vt + (jm * 16 + fr) * 72 + ks * 32 + fq * 8);
            acc[j][jm] = __builtin_amdgcn_mfma_f32_16x16x32_bf16(
                pA, vB, acc[j][jm], 0, 0, 0);
          }
        }
        __syncthreads();  // pt consumed before next j/kti overwrites
      }
    }
    // write out both qt of the pair
#pragma unroll
    for (int j = 0; j < 2; j++) {
      int qg0 = (2 * p + j) * 64 + ql0;
#pragma unroll
      for (int jm = 0; jm < 4; jm++)
#pragma unroll
        for (int rr = 0; rr < 4; rr++)
          y[rowbase + (size_t)(qg0 + rr) * CC + jm * 16 + fr] = acc[j][jm][rr];
    }
  }
}

// ---------------------------------------------------------------------------
// 10. LayerNorm over C -> bf16 (float4 loads/stores)
// ---------------------------------------------------------------------------
__global__ __launch_bounds__(256) void ln_kernel(const float* __restrict__ y,
                                                 const float* __restrict__ g,
                                                 const float* __restrict__ bta,
                                                 u16* __restrict__ out) {
  __shared__ float red[8];
  int bt = blockIdx.x;
  int tid = threadIdx.x;
  float4 v = *(const float4*)(y + (size_t)bt * 1024 + tid * 4);
  float s = v.x + v.y + v.z + v.w;
#pragma unroll
  for (int off = 32; off > 0; off >>= 1) s += __shfl_down(s, off);
  if ((tid & 63) == 0) red[tid >> 6] = s;
  __syncthreads();
  if (tid == 0) red[4] = red[0] + red[1] + red[2] + red[3];
  __syncthreads();
  float mu = red[4] * (1.f / 1024.f);
  float d0 = v.x - mu, d1 = v.y - mu, d2 = v.z - mu, d3 = v.w - mu;
  float s2 = d0 * d0 + d1 * d1 + d2 * d2 + d3 * d3;
#pragma unroll
  for (int off = 32; off > 0; off >>= 1) s2 += __shfl_down(s2, off);
  __syncthreads();
  if ((tid & 63) == 0) red[tid >> 6] = s2;
  __syncthreads();
  if (tid == 0) red[5] = red[0] + red[1] + red[2] + red[3];
  __syncthreads();
  float var = red[5] * (1.f / 1024.f);
  float rstd = rsqrtf(var + 1e-5f);
  float4 g4 = *(const float4*)(g + tid * 4);
  float4 b4 = *(const float4*)(bta + tid * 4);
  u16x4 o;
  o.x = f2b(d0 * rstd * g4.x + b4.x);
  o.y = f2b(d1 * rstd * g4.y + b4.y);
  o.z = f2b(d2 * rstd * g4.z + b4.z);
  o.w = f2b(d3 * rstd * g4.w + b4.w);
  *(u16x4*)(out + (size_t)bt * 1024 + tid * 4) = o;
}

// ---------------------------------------------------------------------------
extern "C" void kernel_launch(void* const* d_in, const int* in_sizes, int n_in,
                              void* d_out, int out_size, void* d_ws,
                              size_t ws_size, hipStream_t stream) {
  const float* x = (const float*)d_in[0];
  const float* tmx = (const float*)d_in[1];
  const float* tmw = (const float*)d_in[2];
  const float* tmk = (const float*)d_in[3];
  const float* tmv = (const float*)d_in[4];
  const float* tmr = (const float*)d_in[5];
  const float* maa_w1 = (const float*)d_in[6];
  const float* maa_w2 = (const float*)d_in[7];
  const float* decay_w1 = (const float*)d_in[8];
  const float* decay_w2 = (const float*)d_in[9];
  const float* time_decay = (const float*)d_in[10];
  const float* faaaa = (const float*)d_in[11];
  const float* Wr = (const float*)d_in[12];
  const float* Wk = (const float*)d_in[13];
  const float* Wv = (const float*)d_in[14];
  const float* Wo = (const float*)d_in[15];
  const float* lng = (const float*)d_in[16];
  const float* lnb = (const float*)d_in[17];
  float* out = (float*)d_out;
  float* ws = (float*)d_ws;

  const size_t S = (size_t)BT * CC;  // 8388608

  // f32 region
  float* y_ = ws;                     // attn out
  float* dw2r = ws + S;               // 1024
  float* tdr = dw2r + 1024;           // pad to 1024
  float* wlog = tdr + 1024;           // 131072
  float* cum = wlog + 131072;
  float* excl = cum + 131072;
  float* wsl = excl + 131072;         // pad to 1024
  float* diagG = wsl + 1024;          // 131072
  float* kvb = diagG + 131072;        // 512*4096
  float* stb = kvb + (size_t)512 * 4096;
  float* fend = stb + (size_t)512 * 4096;
  // bf16 region (u16)
  u16* xxxb = (u16*)fend;             // mix out -> maa GEMM in -> vT
  u16* mb = xxxb + S;                 // BT*128
  u16* xkb = mb + (size_t)BT * 128;   // blend out -> gemm_dp in -> ylnb
  u16* xvb = xkb + S;                 // blend out -> gemm_dp in
  u16* xrb = xvb + S;                 // blend out -> gemm_dp in
  u16* xwb = xrb + S;                 // blend out -> decay_mfma in
  u16* rb16 = xwb + S;                // gemm_dp out
  u16* kb16 = rb16 + S;               // gemm_dp out
  u16* Vb = kb16 + S;                 // gemm_dp out
  u16* Wrt = Vb + S;
  u16* Wkt = Wrt + (size_t)1024 * 1024;
  u16* Wvt = Wkt + (size_t)1024 * 1024;
  u16* Wot = Wvt + (size_t)1024 * 1024;
  u16* w1T = Wot + (size_t)1024 * 1024;   // [128][1024]
  u16* w2T = w1T + (size_t)128 * 1024;    // [1024][128]
  u16* d1T = w2T + (size_t)1024 * 128;    // [64][1024]
  u16* dw2rbT = d1T + (size_t)64 * 1024;  // [16][64]
  // aliases (stream-ordered reuse)
  u16* vT = xxxb;   // kvfuse writes, attn reads (after gemm_maa consumed xxxb)
  u16* ylnb = xkb;  // after gemm_dp consumed xkb

  // allow 72 KB dynamic LDS for the deep-pipelined GEMMs (once per process)
  static bool attr_done = false;
  if (!attr_done) {
    hipFuncSetAttribute((const void*)gemm_dp<true, false>,
                        hipFuncAttributeMaxDynamicSharedMemorySize, DP_SMEM_BYTES);
    hipFuncSetAttribute((const void*)gemm_dp<false, true>,
                        hipFuncAttributeMaxDynamicSharedMemorySize, DP_SMEM_BYTES);
    attr_done = true;
  }

  // merged weight prep (cvt_wT + cvt3_T + dw2r in one launch)
  cvt_all<<<dim3(16, 16, 8), 256, 0, stream>>>(
      Wr, Wk, Wv, Wo, Wrt, Wkt, Wvt, Wot, maa_w1, maa_w2, decay_w1, w1T, w2T,
      d1T, decay_w2, time_decay, dw2r, tdr, dw2rbT);
  mix_kernel<<<8192, 256, 0, stream>>>(x, tmx, xxxb);
  gemm_maa<<<dim3(2, 128), 256, 0, stream>>>(xxxb, w1T, mb);
  blend_mfma<<<dim3(16, 128), 256, 0, stream>>>(mb, w2T, x, tmw, tmk, tmv, tmr,
                                                xwb, xkb, xvb, xrb);
  decay_mfma<<<256, 256, 0, stream>>>(xwb, d1T, dw2rbT, tdr, wlog);
  wprep_kernel<<<512, 256, 0, stream>>>(wlog, cum, excl, wsl);
  // fused r/k/v projections: deep-pipelined GEMM v5 (BK=32, 2 blocks/CU)
  gemm_dp<true, false><<<dim3(4, 64, 3), 512, DP_SMEM_BYTES, stream>>>(
      xrb, xkb, xvb, Wrt, Wkt, Wvt, nullptr, rb16, kb16, Vb);
  // fused transpose + diag + kv
  kvfuse_kernel<<<512, 256, 0, stream>>>(Vb, kb16, rb16, faaaa, cum, wsl, vT,
                                         diagG, kvb);
  scan_kernel<<<256, 256, 0, stream>>>(kvb, wsl, stb);
  attn_mfma<<<512, 256, 0, stream>>>(rb16, kb16, vT, stb, cum, excl, diagG, y_);
  ln_kernel<<<BT, 256, 0, stream>>>(y_, lng, lnb, ylnb);
  // output projection: same deep-pipelined GEMM, f32 out
  gemm_dp<false, true><<<dim3(4, 64, 1), 512, DP_SMEM_BYTES, stream>>>(
      ylnb, nullptr, nullptr, Wot, nullptr, nullptr, out, nullptr, nullptr,
      nullptr);
}

// Round 11
// 346.826 us; speedup vs baseline: 1.0128x; 1.0128x over previous
//
#include <hip/hip_runtime.h>
#include <math.h>

// B=4, T=2048, C=1024, H=16, N=64, Q=256, nc=8, BT=8192
#define BB 4
#define TT 2048
#define CC 1024
#define HH 16
#define NN 64
#define QQ 256
#define NCH 8
#define BT 8192

typedef unsigned short u16;
typedef __attribute__((ext_vector_type(8))) short bf16x8;
typedef __attribute__((ext_vector_type(4))) short bf16x4;
typedef __attribute__((ext_vector_type(4))) float f32x4;
typedef __attribute__((ext_vector_type(4))) u16 u16x4;

// f32 -> bf16 bits, round-to-nearest-even
__device__ inline u16 f2b(float x) {
  union { float f; unsigned u; } v;
  v.f = x;
  unsigned r = v.u + 0x7FFFu + ((v.u >> 16) & 1u);
  return (u16)(r >> 16);
}
__device__ inline float b2f(u16 u) {
  union { unsigned u; float f; } v;
  v.u = ((unsigned)u) << 16;
  return v.f;
}
// 16B fragment from padded LDS row via two 8B loads (conflict-friendly)
__device__ inline bf16x8 ldfrag(const u16* p) {
  bf16x4 lo = *(const bf16x4*)p;
  bf16x4 hi = *(const bf16x4*)(p + 4);
  return __builtin_shufflevector(lo, hi, 0, 1, 2, 3, 4, 5, 6, 7);
}
// stage 64x64 bf16 tile (global pitch `pitch` u16) into LDS stride-72
__device__ inline void stage_tile(const u16* __restrict__ g, size_t base,
                                  int pitch, int tid, u16* __restrict__ lds) {
#pragma unroll
  for (int it = 0; it < 2; it++) {
    int cidx = tid + it * 256;  // 0..511
    int r = cidx >> 3, c8 = (cidx & 7) * 8;
    bf16x8 v = *(const bf16x8*)(g + base + (size_t)r * pitch + c8);
    *(bf16x4*)(lds + r * 72 + c8) = __builtin_shufflevector(v, v, 0, 1, 2, 3);
    *(bf16x4*)(lds + r * 72 + c8 + 4) = __builtin_shufflevector(v, v, 4, 5, 6, 7);
  }
}

// ---------------------------------------------------------------------------
// 1. time-shift mix: xxx -> bf16 only (xx recomputed inline in blend)
// ---------------------------------------------------------------------------
__global__ __launch_bounds__(256) void mix_kernel(const float* __restrict__ x,
                                                  const float* __restrict__ tmx,
                                                  u16* __restrict__ xxxb) {
  size_t e = ((size_t)blockIdx.x * 256 + threadIdx.x) * 4;
  int c = (int)(e & 1023);
  size_t row = e >> 10;
  int t = (int)(row & 2047);
  float4 xv = *(const float4*)(x + e);
  float4 pv = make_float4(0.f, 0.f, 0.f, 0.f);
  if (t > 0) pv = *(const float4*)(x + e - 1024);
  float4 d = make_float4(pv.x - xv.x, pv.y - xv.y, pv.z - xv.z, pv.w - xv.w);
  u16x4 o;
  o.x = f2b(xv.x + d.x * tmx[c + 0]);
  o.y = f2b(xv.y + d.y * tmx[c + 1]);
  o.z = f2b(xv.z + d.z * tmx[c + 2]);
  o.w = f2b(xv.w + d.w * tmx[c + 3]);
  *(u16x4*)(xxxb + e) = o;
}

// ---------------------------------------------------------------------------
// merged weight prep (ONE launch), grid (16,16,8):
//   z<4 : big 1024x1024 weight f32[k][n] -> bf16 Wt[n][k]
//   z=4 : maa_w1 f32[1024][128] -> w1T bf16[128][1024]
//   z=5 : maa_w2 f32[128][1024] -> w2T bf16[1024][128]
//   z=6 : decay_w1 f32[1024][64] -> d1T bf16[64][1024]
//   z=7 : dw2r reduce (blocks x<4, y==0 only)
// out-of-range tiles return immediately.
// ---------------------------------------------------------------------------
__global__ __launch_bounds__(256) void cvt_all(
    const float* __restrict__ W0, const float* __restrict__ W1,
    const float* __restrict__ W2, const float* __restrict__ W3,
    u16* __restrict__ O0, u16* __restrict__ O1, u16* __restrict__ O2,
    u16* __restrict__ O3, const float* __restrict__ w1,
    const float* __restrict__ w2, const float* __restrict__ d1,
    u16* __restrict__ o1, u16* __restrict__ o2, u16* __restrict__ o3,
    const float* __restrict__ dw2, const float* __restrict__ td,
    float* __restrict__ dw2r, float* __restrict__ tdr,
    u16* __restrict__ dw2rbT) {
  int z = blockIdx.z;
  if (z == 7) {
    if (blockIdx.y != 0 || blockIdx.x >= 4) return;
    int idx = blockIdx.x * 256 + threadIdx.x;
    if (idx < 1024) {
      int j = idx >> 4, h = idx & 15;
      float s = 0.f;
      for (int n = 0; n < 64; n++) s += dw2[(size_t)j * 1024 + h * 64 + n];
      float m = s * (1.f / 64.f);
      dw2r[j * 16 + h] = m;
      dw2rbT[h * 64 + j] = f2b(m);
    }
    if (idx < 16) {
      float s = 0.f;
      for (int n = 0; n < 64; n++) s += td[idx * 64 + n];
      tdr[idx] = s * (1.f / 64.f);
    }
    return;
  }
  const float* in;
  u16* out;
  int R, C;
  switch (z) {
    case 0: in = W0; out = O0; R = 1024; C = 1024; break;
    case 1: in = W1; out = O1; R = 1024; C = 1024; break;
    case 2: in = W2; out = O2; R = 1024; C = 1024; break;
    case 3: in = W3; out = O3; R = 1024; C = 1024; break;
    case 4: in = w1; out = o1; R = 1024; C = 128; break;
    case 5: in = w2; out = o2; R = 128; C = 1024; break;
    default: in = d1; out = o3; R = 1024; C = 64; break;
  }
  int c0 = blockIdx.x * 64, r0 = blockIdx.y * 64;
  if (c0 >= C || r0 >= R) return;
  __shared__ float t[64][65];
#pragma unroll
  for (int it = 0; it < 16; it++) {
    int idx = it * 256 + threadIdx.x;
    int r = idx >> 6, c = idx & 63;
    t[r][c] = in[(size_t)(r0 + r) * C + c0 + c];
  }
  __syncthreads();
#pragma unroll
  for (int it = 0; it < 16; it++) {
    int idx = it * 256 + threadIdx.x;
    int c = idx >> 6, r = idx & 63;
    out[(size_t)(c0 + c) * R + r0 + r] = f2b(t[r][c]);
  }
}

// ---------------------------------------------------------------------------
// maa GEMM: mb = tanh(xxx @ w1) : A[8192][1024] x w1T[128][1024] -> [8192][128]
// 64x64 tiles -> grid (2,128) = 256 blocks (full-CU coverage).
// ---------------------------------------------------------------------------
__global__ __launch_bounds__(256) void gemm_maa(const u16* __restrict__ A,
                                                const u16* __restrict__ Bt,
                                                u16* __restrict__ Cb) {
  __shared__ u16 As[64 * 32];
  __shared__ u16 Bs[64 * 32];
  const int tid = threadIdx.x;
  const int lane = tid & 63;
  const int wave = tid >> 6;
  const int wc = wave * 16;
  const int fr = lane & 15;
  const int fq = lane >> 4;
  const int row0 = blockIdx.y * 64;
  const int col0 = blockIdx.x * 64;

  f32x4 acc[4];
#pragma unroll
  for (int i = 0; i < 4; i++) acc[i] = (f32x4){0.f, 0.f, 0.f, 0.f};

  const int ra = tid >> 2, ca = (tid & 3) * 8;

  for (int k0 = 0; k0 < 1024; k0 += 32) {
    __builtin_amdgcn_global_load_lds(
        (const __attribute__((address_space(1))) void*)(A + (size_t)(row0 + ra) * 1024 + k0 + ca),
        (__attribute__((address_space(3))) void*)(As + tid * 8), 16, 0, 0);
    __builtin_amdgcn_global_load_lds(
        (const __attribute__((address_space(1))) void*)(Bt + (size_t)(col0 + ra) * 1024 + k0 + ca),
        (__attribute__((address_space(3))) void*)(Bs + tid * 8), 16, 0, 0);
    __syncthreads();
    bf16x8 bf = *(const bf16x8*)(Bs + ((wc + fr) * 32 + fq * 8));
#pragma unroll
    for (int i = 0; i < 4; i++) {
      bf16x8 af = *(const bf16x8*)(As + ((i * 16 + fr) * 32 + fq * 8));
      acc[i] = __builtin_amdgcn_mfma_f32_16x16x32_bf16(af, bf, acc[i], 0, 0, 0);
    }
    __syncthreads();
  }
#pragma unroll
  for (int i = 0; i < 4; i++) {
    int grow = row0 + i * 16 + fq * 4;
#pragma unroll
    for (int r = 0; r < 4; r++)
      Cb[(size_t)(grow + r) * 128 + col0 + wc + fr] = f2b(tanhf(acc[i][r]));
  }
}

// ---------------------------------------------------------------------------
// Deep-pipelined bf16 GEMM v5b: M=8192, N=1024, K=1024.
// BM=128 x BN=256 x BK=32, 512 threads (8 waves, 64x64 wave tiles).
// 3 LDS buffers x 24 KB = 72 KB -> 2 blocks/CU. Depth-2 prefetch, counted
// vmcnt(3), raw s_barrier (1 per K-tile, 32 tiles).
// SWIZZLE FIX vs v5: s(row) = (row>>1)&3 (was row&3). With 64B rows, even
// rows share banks 0-15 and odd rows banks 16-31; row&3 gave only 2 distinct
// chunks among the 8 same-parity lanes of a quarter -> 4-way conflict
// (6.29M measured). (row>>1)&3 spreads them across all 4 chunks -> 2 lanes
// per 4-bank slot = free (m136). Both sides use the same involution:
// stage gch = (pos&3) ^ ((r>>1)&3); read chunk = fq ^ ((fr>>1)&3)
// (row = wr + mi*16 + fr has disjoint bitfields so (row>>1)&3 == (fr>>1)&3).
// grid (4, 64, gz); nwg % 8 == 0; bijective XCD swizzle.
// ---------------------------------------------------------------------------
#define DP_ABUF 4096    /* u16: 128*32 */
#define DP_BBUF 8192    /* u16: 256*32 */
#define DP_SBUF 12288   /* u16 per buffer (24 KB) */
#define DP_SMEM_BYTES 73728 /* 3 buffers = 72 KB */

template <bool TRIPLE, bool F32OUT>
__global__ __launch_bounds__(512, 2) void gemm_dp(
    const u16* __restrict__ A0, const u16* __restrict__ A1,
    const u16* __restrict__ A2, const u16* __restrict__ B0,
    const u16* __restrict__ B1, const u16* __restrict__ B2,
    float* __restrict__ Cf, u16* __restrict__ C0, u16* __restrict__ C1,
    u16* __restrict__ C2) {
  extern __shared__ __align__(16) u16 smem[];
  // T1: bijective XCD swizzle over flattened grid (x fastest; gridDim=(4,64,z))
  const int nwg = (int)(gridDim.x * gridDim.y * gridDim.z);
  const int wg = (int)(blockIdx.x + (blockIdx.y << 2) + (blockIdx.z << 8));
  const int cpx = nwg >> 3;
  const int swz = (wg & 7) * cpx + (wg >> 3);
  const int bx = swz & 3;
  const int by = (swz >> 2) & 63;
  const int bz = swz >> 8;

  const u16* __restrict__ A;
  const u16* __restrict__ Bt;
  u16* __restrict__ Cb;
  if (TRIPLE) {
    switch (bz) {
      case 0: A = A0; Bt = B0; Cb = C0; break;
      case 1: A = A1; Bt = B1; Cb = C1; break;
      default: A = A2; Bt = B2; Cb = C2; break;
    }
  } else {
    A = A0; Bt = B0; Cb = C0;
  }

  const int tid = threadIdx.x;
  const int lane = tid & 63;
  const int wave = tid >> 6;        // 0..7
  const int wr = (wave >> 2) * 64;  // 0 / 64
  const int wc = (wave & 3) * 64;   // 0 / 64 / 128 / 192
  const int fr = lane & 15;
  const int fq = lane >> 4;
  const int s4 = (fr >> 1) & 3;     // == (frag row >> 1) & 3
  const int row0 = by * 128;
  const int col0 = bx * 256;

  // per-lane LDS frag offsets (u16 units), loop-invariant; single K-slice
  int aoff[4], boff[4];
#pragma unroll
  for (int mi = 0; mi < 4; mi++)
    aoff[mi] = (wr + mi * 16 + fr) * 32 + ((fq ^ s4) * 8);
#pragma unroll
  for (int nj = 0; nj < 4; nj++)
    boff[nj] = (wc + nj * 16 + fr) * 32 + ((fq ^ s4) * 8);

  // stage tile kt (3 x 16B per thread: A 1, B 2) into buffer q; global source
  // pre-swizzled so linear LDS dest + swizzled read = consistent involution.
  auto stage = [&](int kt, int q) {
    const u16* __restrict__ gA = A + (size_t)row0 * 1024 + kt * 32;
    const u16* __restrict__ gB = Bt + (size_t)col0 * 1024 + kt * 32;
    u16* dA = smem + q * DP_SBUF;
    u16* dB = dA + DP_ABUF;
    {
      int pos = tid;                    // 0..511 (A: 128 rows x 4 chunks)
      int r = pos >> 2, gch = (pos & 3) ^ ((r >> 1) & 3);
      __builtin_amdgcn_global_load_lds(
          (const __attribute__((address_space(1))) void*)(gA + (size_t)r * 1024 + gch * 8),
          (__attribute__((address_space(3))) void*)(dA + pos * 8), 16, 0, 0);
    }
#pragma unroll
    for (int p = 0; p < 2; p++) {
      int pos = tid + p * 512;          // 0..1023 (B: 256 rows x 4 chunks)
      int r = pos >> 2, gch = (pos & 3) ^ ((r >> 1) & 3);
      __builtin_amdgcn_global_load_lds(
          (const __attribute__((address_space(1))) void*)(gB + (size_t)r * 1024 + gch * 8),
          (__attribute__((address_space(3))) void*)(dB + pos * 8), 16, 0, 0);
    }
  };

  f32x4 acc[4][4];
#pragma unroll
  for (int mi = 0; mi < 4; mi++)
#pragma unroll
    for (int nj = 0; nj < 4; nj++) acc[mi][nj] = (f32x4){0.f, 0.f, 0.f, 0.f};

  auto iter_body = [&](int qc, int qs, bool dostage, int t2) {
    if (dostage) stage(t2, qs);  // issue next+1 tile loads early
    const u16* sA = smem + qc * DP_SBUF;
    const u16* sB = sA + DP_ABUF;
    bf16x8 av[4], bv[4];
#pragma unroll
    for (int mi = 0; mi < 4; mi++) av[mi] = *(const bf16x8*)(sA + aoff[mi]);
#pragma unroll
    for (int nj = 0; nj < 4; nj++) bv[nj] = *(const bf16x8*)(sB + boff[nj]);
    __builtin_amdgcn_s_setprio(1);
#pragma unroll
    for (int mi = 0; mi < 4; mi++)
#pragma unroll
      for (int nj = 0; nj < 4; nj++)
        acc[mi][nj] = __builtin_amdgcn_mfma_f32_16x16x32_bf16(
            av[mi], bv[nj], acc[mi][nj], 0, 0, 0);
    __builtin_amdgcn_s_setprio(0);
  };

  // prologue: 2 tiles in flight (6 loads)
  stage(0, 0);
  stage(1, 1);
  int qc = 0, qs = 2;
  // main loop: wait current tile (vmcnt 3: leaves next tile's 3 in flight)
  for (int t = 0; t < 30; t++) {
    asm volatile("s_waitcnt vmcnt(3)" ::: "memory");
    __builtin_amdgcn_s_barrier();
    iter_body(qc, qs, true, t + 2);
    qc = (qc == 2) ? 0 : qc + 1;
    qs = (qs == 2) ? 0 : qs + 1;
  }
  // t = 30: no more staging; tile 31's 3 loads remain in flight
  asm volatile("s_waitcnt vmcnt(3)" ::: "memory");
  __builtin_amdgcn_s_barrier();
  iter_body(qc, 0, false, 0);
  qc = (qc == 2) ? 0 : qc + 1;
  // t = 31: drain
  asm volatile("s_waitcnt vmcnt(0)" ::: "memory");
  __builtin_amdgcn_s_barrier();
  iter_body(qc, 0, false, 0);

#pragma unroll
  for (int mi = 0; mi < 4; mi++) {
    int grow = row0 + wr + mi * 16 + fq * 4;
#pragma unroll
    for (int nj = 0; nj < 4; nj++) {
      int gcol = col0 + wc + nj * 16 + fr;
#pragma unroll
      for (int r = 0; r < 4; r++) {
        if (F32OUT)
          Cf[(size_t)(grow + r) * 1024 + gcol] = acc[mi][nj][r];
        else
          Cb[(size_t)(grow + r) * 1024 + gcol] = f2b(acc[mi][nj][r]);
      }
    }
  }
}

// ---------------------------------------------------------------------------
// 3. blend via MFMA (fused x/xx/tm* epilogue); xx recomputed inline from x.
// ---------------------------------------------------------------------------
__global__ __launch_bounds__(256) void blend_mfma(
    const u16* __restrict__ mb, const u16* __restrict__ w2T,
    const float* __restrict__ x,
    const float* __restrict__ tmw, const float* __restrict__ tmk,
    const float* __restrict__ tmv, const float* __restrict__ tmr,
    u16* __restrict__ xwb, u16* __restrict__ xkb, u16* __restrict__ xvb,
    u16* __restrict__ xrb) {
  __shared__ u16 mS[64 * 136];
  __shared__ u16 wS[64 * 136];
  const int tid = threadIdx.x;
  const int lane = tid & 63;
  const int w = tid >> 6;
  const int fr = lane & 15;
  const int fq = lane >> 4;
  const int c0 = blockIdx.x * 64;
  const int bt0 = blockIdx.y * 64;

#pragma unroll
  for (int it = 0; it < 4; it++) {
    int idx = tid + it * 256;  // 0..1023
    int r = idx >> 4, c8 = (idx & 15) * 8;
    bf16x8 v = *(const bf16x8*)(mb + (size_t)(bt0 + r) * 128 + c8);
    *(bf16x4*)(mS + r * 136 + c8) = __builtin_shufflevector(v, v, 0, 1, 2, 3);
    *(bf16x4*)(mS + r * 136 + c8 + 4) = __builtin_shufflevector(v, v, 4, 5, 6, 7);
    bf16x8 u = *(const bf16x8*)(w2T + (size_t)(c0 + r) * 128 + c8);
    *(bf16x4*)(wS + r * 136 + c8) = __builtin_shufflevector(u, u, 0, 1, 2, 3);
    *(bf16x4*)(wS + r * 136 + c8 + 4) = __builtin_shufflevector(u, u, 4, 5, 6, 7);
  }
  __syncthreads();

  f32x4 acc[4][4];  // [col-tile j][f]
#pragma unroll
  for (int j = 0; j < 4; j++)
#pragma unroll
    for (int f = 0; f < 4; f++) acc[j][f] = (f32x4){0.f, 0.f, 0.f, 0.f};

#pragma unroll
  for (int f = 0; f < 4; f++) {
    bf16x8 aA = ldfrag(mS + (w * 16 + fr) * 136 + f * 32 + fq * 8);
#pragma unroll
    for (int j = 0; j < 4; j++) {
      bf16x8 bB = ldfrag(wS + (j * 16 + fr) * 136 + f * 32 + fq * 8);
      acc[j][f] = __builtin_amdgcn_mfma_f32_16x16x32_bf16(aA, bB, acc[j][f], 0, 0, 0);
    }
  }

#pragma unroll
  for (int j = 0; j < 4; j++) {
    int c = c0 + j * 16 + fr;
    float w_ = tmw[c], k_ = tmk[c], v_ = tmv[c], r_ = tmr[c];
#pragma unroll
    for (int rr = 0; rr < 4; rr++) {
      int bt = bt0 + w * 16 + fq * 4 + rr;
      size_t g = (size_t)bt * 1024 + c;
      float xv_ = x[g];
      float xp = ((bt & 2047) != 0) ? x[g - 1024] : 0.f;
      float dx = xp - xv_;
      xwb[g] = f2b(xv_ + dx * (w_ + acc[j][0][rr]));
      xkb[g] = f2b(xv_ + dx * (k_ + acc[j][1][rr]));
      xvb[g] = f2b(xv_ + dx * (v_ + acc[j][2][rr]));
      xrb[g] = f2b(xv_ + dx * (r_ + acc[j][3][rr]));
    }
  }
}

// ---------------------------------------------------------------------------
// 5b. fused decay GEMM: h1 = tanh(xw @ d1) via MFMA (K=1024), then
//     wlog = -exp(tdr + h1 @ dw2r). 32-row tiles -> 256 blocks (full CU
//     coverage); BK=64 with gemm_dp's XOR chunk-swizzle recipe.
// ---------------------------------------------------------------------------
__global__ __launch_bounds__(256) void decay_mfma(const u16* __restrict__ xwb,
                                                  const u16* __restrict__ d1T,
                                                  const u16* __restrict__ dw2rbT,
                                                  const float* __restrict__ tdr,
                                                  float* __restrict__ wlog) {
  __shared__ u16 As[32 * 64];
  __shared__ u16 Bs[64 * 64];
  __shared__ u16 h1S[32 * 72];
  __shared__ u16 dwS[16 * 72];
  const int tid = threadIdx.x;
  const int lane = tid & 63;
  const int w = tid >> 6;
  const int fr = lane & 15;
  const int fq = lane >> 4;
  const int s8 = fr & 7;
  const int bt0 = blockIdx.x * 32;

#pragma unroll
  for (int it = 0; it < 4; it++) {
    int idx = tid + it * 256;
    int r = idx >> 6, c = idx & 63;
    dwS[r * 72 + c] = dw2rbT[r * 64 + c];
  }

  f32x4 acc[2];
#pragma unroll
  for (int mi = 0; mi < 2; mi++) acc[mi] = (f32x4){0.f, 0.f, 0.f, 0.f};

  const int raA = tid >> 3;              // 0..31
  const int gchA = (tid & 7) ^ (raA & 7);

  for (int k0 = 0; k0 < 1024; k0 += 64) {
    __builtin_amdgcn_global_load_lds(
        (const __attribute__((address_space(1))) void*)(
            xwb + (size_t)(bt0 + raA) * 1024 + k0 + gchA * 8),
        (__attribute__((address_space(3))) void*)(As + tid * 8), 16, 0, 0);
#pragma unroll
    for (int p = 0; p < 2; p++) {
      int pos = tid + p * 256;           // 0..511
      int r = pos >> 3, gch = (pos & 7) ^ (r & 7);
      __builtin_amdgcn_global_load_lds(
          (const __attribute__((address_space(1))) void*)(
              d1T + (size_t)r * 1024 + k0 + gch * 8),
          (__attribute__((address_space(3))) void*)(Bs + pos * 8), 16, 0, 0);
    }
    __syncthreads();
#pragma unroll
    for (int ks = 0; ks < 2; ks++) {
      int chunk = ((ks * 4 + fq) ^ s8) * 8;
      bf16x8 bB = *(const bf16x8*)(Bs + (w * 16 + fr) * 64 + chunk);
#pragma unroll
      for (int mi = 0; mi < 2; mi++) {
        bf16x8 aA = *(const bf16x8*)(As + (mi * 16 + fr) * 64 + chunk);
        acc[mi] = __builtin_amdgcn_mfma_f32_16x16x32_bf16(aA, bB, acc[mi], 0, 0, 0);
      }
    }
    __syncthreads();
  }
#pragma unroll
  for (int mi = 0; mi < 2; mi++)
#pragma unroll
    for (int rr = 0; rr < 4; rr++)
      h1S[(mi * 16 + fq * 4 + rr) * 72 + w * 16 + fr] = f2b(tanhf(acc[mi][rr]));
  __syncthreads();

  if (w < 2) {
    f32x4 a2 = (f32x4){0.f, 0.f, 0.f, 0.f};
#pragma unroll
    for (int ks = 0; ks < 2; ks++) {
      bf16x8 aA = ldfrag(h1S + (w * 16 + fr) * 72 + ks * 32 + fq * 8);
      bf16x8 bB = ldfrag(dwS + fr * 72 + ks * 32 + fq * 8);
      a2 = __builtin_amdgcn_mfma_f32_16x16x32_bf16(aA, bB, a2, 0, 0, 0);
    }
    float tdv = tdr[fr];
#pragma unroll
    for (int rr = 0; rr < 4; rr++) {
      int bt = bt0 + w * 16 + fq * 4 + rr;
      int b = bt >> 11, tl = bt & 2047;
      wlog[((size_t)(b * 16 + fr)) * 2048 + tl] = -__expf(tdv + a2[rr]);
    }
  }
}

// ---------------------------------------------------------------------------
// 7. per-chunk scan
// ---------------------------------------------------------------------------
__global__ __launch_bounds__(256) void wprep_kernel(const float* __restrict__ wlog,
                                                    float* __restrict__ cum,
                                                    float* __restrict__ excl,
                                                    float* __restrict__ wsl) {
  int bid = blockIdx.x;
  int c = bid & 7, bh = bid >> 3;
  int q = threadIdx.x;
  float v = wlog[(size_t)bh * 2048 + c * 256 + q];
  __shared__ float s[256];
  s[q] = v;
  float val = v;
  for (int off = 1; off < 256; off <<= 1) {
    __syncthreads();
    float t = (q >= off) ? s[q - off] : 0.f;
    __syncthreads();
    val += t;
    s[q] = val;
  }
  __syncthreads();
  float total = s[255];
  cum[(size_t)bid * 256 + q] = val;
  excl[(size_t)bid * 256 + q] = val - v;
  if (q == 0) wsl[bid] = total;
}

// ---------------------------------------------------------------------------
// kvfuse: per (bh, chunk) block — transpose k,v quarters into LDS, compute
// diag (full-wave reduce), write vT (global, for attn), and accumulate
// kv = (k*w_inter)^T @ v via MFMA in the same kernel.
// ---------------------------------------------------------------------------
__global__ __launch_bounds__(256) void kvfuse_kernel(
    const u16* __restrict__ vb, const u16* __restrict__ kb,
    const u16* __restrict__ rb, const float* __restrict__ faaaa,
    const float* __restrict__ cum, const float* __restrict__ wsl,
    u16* __restrict__ vT, float* __restrict__ diagG, float* __restrict__ kvb) {
  int bid = blockIdx.x;
  int c = bid & 7, bh = bid >> 3;
  int b = bh >> 4, h = bh & 15;
  __shared__ float tv[64][65];
  __shared__ float tk[64][65];
  __shared__ u16 kSb[64 * 72];
  __shared__ u16 vSb[64 * 72];
  __shared__ float wfacS[256];
  __shared__ float faS[64];
  const int tid = threadIdx.x;
  const int lane = tid & 63;
  const int w = tid >> 6;
  const int fr = lane & 15;
  const int fq = lane >> 4;
  const int m = lane;

  float wslog = wsl[bid];
  wfacS[tid] = __expf(wslog - cum[(size_t)bid * 256 + tid]);
  if (tid < 64) faS[tid] = faaaa[h * 64 + tid];

  f32x4 acc[4];
#pragma unroll
  for (int j = 0; j < 4; j++) acc[j] = (f32x4){0.f, 0.f, 0.f, 0.f};

  for (int qt = 0; qt < 4; qt++) {
    __syncthreads();  // tv/tk free (prev transpose done); wfacS/faS ready
    float fam = faS[m];
    int t0 = c * QQ + qt * 64;
#pragma unroll
    for (int it = 0; it < 16; it++) {
      int r = it * 4 + w;
      size_t g = ((size_t)(b * TT + t0 + r)) * CC + h * 64 + m;
      float vraw = b2f(vb[g]);
      float kraw = b2f(kb[g]);
      float rraw = b2f(rb[g]);
      tv[r][m] = vraw;
      tk[r][m] = kraw;
      float s = rraw * fam * kraw;
      s += __shfl_xor(s, 1);
      s += __shfl_xor(s, 2);
      s += __shfl_xor(s, 4);
      s += __shfl_xor(s, 8);
      s += __shfl_xor(s, 16);
      s += __shfl_xor(s, 32);
      if (m == 0) diagG[(size_t)bh * 2048 + t0 + r] = s;
    }
    __syncthreads();
#pragma unroll
    for (int it = 0; it < 16; it++) {
      int idx = it * 256 + tid;
      int mm = idx >> 6, tl = idx & 63;
      float vv = tv[tl][mm];
      float kk = tk[tl][mm] * wfacS[qt * 64 + tl];
      u16 vbv = f2b(vv);
      vT[((size_t)(bh * 64 + mm)) * TT + t0 + tl] = vbv;
      vSb[mm * 72 + tl] = vbv;
      kSb[mm * 72 + tl] = f2b(kk);
    }
    __syncthreads();
#pragma unroll
    for (int ks = 0; ks < 2; ks++) {
      bf16x8 aA = ldfrag(kSb + (w * 16 + fr) * 72 + ks * 32 + fq * 8);
#pragma unroll
      for (int j = 0; j < 4; j++) {
        bf16x8 bB = ldfrag(vSb + (j * 16 + fr) * 72 + ks * 32 + fq * 8);
        acc[j] = __builtin_amdgcn_mfma_f32_16x16x32_bf16(aA, bB, acc[j], 0, 0, 0);
      }
    }
  }
#pragma unroll
  for (int j = 0; j < 4; j++)
#pragma unroll
    for (int rr = 0; rr < 4; rr++)
      kvb[(size_t)bid * 4096 + (w * 16 + fq * 4 + rr) * 64 + j * 16 + fr] = acc[j][rr];
}

// ---------------------------------------------------------------------------
// 8b. sequential state scan over chunks — 256 blocks (bh x 4 slices), float4
// ---------------------------------------------------------------------------
__global__ __launch_bounds__(256) void scan_kernel(const float* __restrict__ kvb,
                                                   const float* __restrict__ wsl,
                                                   float* __restrict__ st) {
  int bh = blockIdx.x >> 2;
  int sl = blockIdx.x & 3;
  int tid = threadIdx.x;
  f32x4 s = (f32x4){0.f, 0.f, 0.f, 0.f};
  for (int c = 0; c < 8; c++) {
    int bid = bh * 8 + c;
    float w = __expf(wsl[bid]);
    size_t e = (size_t)bid * 4096 + sl * 1024 + tid * 4;
    f32x4 kv = *(const f32x4*)(kvb + e);
    *(f32x4*)(st + e) = s;
    s = w * s + kv;
  }
}

// ---------------------------------------------------------------------------
// 9. MFMA fused attention — qt-PAIR blocking:
// process qt in pairs {2p, 2p+1}: hold acc[2][4] + rA[2][2] in registers,
// stage rt(2p+1) into the idle pt slot, loop kti once per pair.
// Mask via factored exp tables; diag from diagG.
// ---------------------------------------------------------------------------
__global__ __launch_bounds__(256) void attn_mfma(
    const u16* __restrict__ rb, const u16* __restrict__ kb,
    const u16* __restrict__ vT, const float* __restrict__ stg,
    const float* __restrict__ cum, const float* __restrict__ excl,
    const float* __restrict__ diagG, float* __restrict__ y) {
  int bid = blockIdx.x;
  int c = bid & 7, bh = bid >> 3;
  int b = bh >> 4, h = bh & 15;
  __shared__ u16 rt[64 * 72];
  __shared__ u16 kt[64 * 72];
  __shared__ u16 vt[64 * 72];
  __shared__ u16 pt[64 * 72];
  __shared__ u16 stT[64 * 72];
  __shared__ float cumS[256], exS[256], diagS[256], ekS[256];

  const int tid = threadIdx.x;
  const int lane = tid & 63;
  const int w = tid >> 6;
  const int fr = lane & 15;
  const int fq = lane >> 4;

  cumS[tid] = cum[(size_t)bid * 256 + tid];
  exS[tid] = excl[(size_t)bid * 256 + tid];
  diagS[tid] = diagG[(size_t)bh * 2048 + c * 256 + tid];
#pragma unroll
  for (int it = 0; it < 16; it++) {
    int idx = tid + it * 256;
    int n = idx >> 6, mm = idx & 63;
    stT[mm * 72 + n] = f2b(stg[(size_t)bid * 4096 + idx]);
  }
  __syncthreads();
  const float ccm = cumS[127];
  ekS[tid] = __expf(ccm - cumS[tid]);

  const size_t rowbase = ((size_t)b * TT + c * QQ) * CC + h * 64;
  const size_t vbase0 = (size_t)bh * 64 * TT + c * QQ;
  const int ql0 = w * 16 + fq * 4;

#pragma unroll
  for (int p = 0; p < 2; p++) {
    __syncthreads();  // prev pair's pt/kt/vt reads complete (p=1); noop-safe p=0
    stage_tile(rb, rowbase + (size_t)((2 * p) * 64) * CC, CC, tid, rt);
    stage_tile(rb, rowbase + (size_t)((2 * p + 1) * 64) * CC, CC, tid, pt);
    __syncthreads();
    bf16x8 rA[2][2];
    rA[0][0] = ldfrag(rt + (w * 16 + fr) * 72 + fq * 8);
    rA[0][1] = ldfrag(rt + (w * 16 + fr) * 72 + 32 + fq * 8);
    rA[1][0] = ldfrag(pt + (w * 16 + fr) * 72 + fq * 8);
    rA[1][1] = ldfrag(pt + (w * 16 + fr) * 72 + 32 + fq * 8);

    f32x4 acc[2][4];
    float eqc[2][4];
#pragma unroll
    for (int j = 0; j < 2; j++) {
      int qt = 2 * p + j;
#pragma unroll
      for (int jm = 0; jm < 4; jm++) acc[j][jm] = (f32x4){0.f, 0.f, 0.f, 0.f};
#pragma unroll
      for (int ks = 0; ks < 2; ks++)
#pragma unroll
        for (int jm = 0; jm < 4; jm++) {
          bf16x8 bB = ldfrag(stT + (jm * 16 + fr) * 72 + ks * 32 + fq * 8);
          acc[j][jm] = __builtin_amdgcn_mfma_f32_16x16x32_bf16(
              rA[j][ks], bB, acc[j][jm], 0, 0, 0);
        }
      float er[4];
#pragma unroll
      for (int rr = 0; rr < 4; rr++) {
        float ex = exS[qt * 64 + ql0 + rr];
        er[rr] = __expf(ex);
        eqc[j][rr] = __expf(ex - ccm);
      }
#pragma unroll
      for (int jm = 0; jm < 4; jm++)
#pragma unroll
        for (int rr = 0; rr < 4; rr++) acc[j][jm][rr] *= er[rr];
    }

#pragma unroll
    for (int kti = 0; kti < 2 * p + 2; kti++) {
      __syncthreads();  // rA[1] frag reads (kti=0) / prev PV pt reads done
      stage_tile(kb, rowbase + (size_t)(kti * 64) * CC, CC, tid, kt);
      stage_tile(vT, vbase0 + (size_t)(kti * 64), TT, tid, vt);
      __syncthreads();
#pragma unroll
      for (int j = 0; j < 2; j++) {
        int qt = 2 * p + j;
        if (kti > qt) continue;  // compile-time resolved (all loops unrolled)
        f32x4 sacc[4];
#pragma unroll
        for (int jj = 0; jj < 4; jj++) sacc[jj] = (f32x4){0.f, 0.f, 0.f, 0.f};
#pragma unroll
        for (int ks = 0; ks < 2; ks++)
#pragma unroll
          for (int jj = 0; jj < 4; jj++) {
            bf16x8 bB = ldfrag(kt + (jj * 16 + fr) * 72 + ks * 32 + fq * 8);
            sacc[jj] = __builtin_amdgcn_mfma_f32_16x16x32_bf16(
                rA[j][ks], bB, sacc[jj], 0, 0, 0);
          }
#pragma unroll
        for (int jj = 0; jj < 4; jj++) {
          int kcol = kti * 64 + jj * 16 + fr;
          float ek = ekS[kcol];
#pragma unroll
          for (int rr = 0; rr < 4; rr++) {
            int qrow = qt * 64 + ql0 + rr;
            float vsc;
            if (kcol < qrow)
              vsc = sacc[jj][rr] * eqc[j][rr] * ek;
            else if (kcol == qrow)
              vsc = diagS[qrow];
            else
              vsc = 0.f;
            pt[(ql0 + rr) * 72 + jj * 16 + fr] = f2b(vsc);
          }
        }
        __syncthreads();
#pragma unroll
        for (int ks = 0; ks < 2; ks++) {
          bf16x8 pA = ldfrag(pt + (w * 16 + fr) * 72 + ks * 32 + fq * 8);
#pragma unroll
          for (int jm = 0; jm < 4; jm++) {
            bf16x8 vB = ldfrag(vt + (jm * 16 + fr) * 72 + ks * 32 + fq * 8);
            acc[j][jm] = __builtin_amdgcn_mfma_f32_16x16x32_bf16(
                pA, vB, acc[j][jm], 0, 0, 0);
          }
        }
        __syncthreads();  // pt consumed before next j/kti overwrites
      }
    }
    // write out both qt of the pair
#pragma unroll
    for (int j = 0; j < 2; j++) {
      int qg0 = (2 * p + j) * 64 + ql0;
#pragma unroll
      for (int jm = 0; jm < 4; jm++)
#pragma unroll
        for (int rr = 0; rr < 4; rr++)
          y[rowbase + (size_t)(qg0 + rr) * CC + jm * 16 + fr] = acc[j][jm][rr];
    }
  }
}

// ---------------------------------------------------------------------------
// 10. LayerNorm over C -> bf16 (float4 loads/stores)
// ---------------------------------------------------------------------------
__global__ __launch_bounds__(256) void ln_kernel(const float* __restrict__ y,
                                                 const float* __restrict__ g,
                                                 const float* __restrict__ bta,
                                                 u16* __restrict__ out) {
  __shared__ float red[8];
  int bt = blockIdx.x;
  int tid = threadIdx.x;
  float4 v = *(const float4*)(y + (size_t)bt * 1024 + tid * 4);
  float s = v.x + v.y + v.z + v.w;
#pragma unroll
  for (int off = 32; off > 0; off >>= 1) s += __shfl_down(s, off);
  if ((tid & 63) == 0) red[tid >> 6] = s;
  __syncthreads();
  if (tid == 0) red[4] = red[0] + red[1] + red[2] + red[3];
  __syncthreads();
  float mu = red[4] * (1.f / 1024.f);
  float d0 = v.x - mu, d1 = v.y - mu, d2 = v.z - mu, d3 = v.w - mu;
  float s2 = d0 * d0 + d1 * d1 + d2 * d2 + d3 * d3;
#pragma unroll
  for (int off = 32; off > 0; off >>= 1) s2 += __shfl_down(s2, off);
  __syncthreads();
  if ((tid & 63) == 0) red[tid >> 6] = s2;
  __syncthreads();
  if (tid == 0) red[5] = red[0] + red[1] + red[2] + red[3];
  __syncthreads();
  float var = red[5] * (1.f / 1024.f);
  float rstd = rsqrtf(var + 1e-5f);
  float4 g4 = *(const float4*)(g + tid * 4);
  float4 b4 = *(const float4*)(bta + tid * 4);
  u16x4 o;
  o.x = f2b(d0 * rstd * g4.x + b4.x);
  o.y = f2b(d1 * rstd * g4.y + b4.y);
  o.z = f2b(d2 * rstd * g4.z + b4.z);
  o.w = f2b(d3 * rstd * g4.w + b4.w);
  *(u16x4*)(out + (size_t)bt * 1024 + tid * 4) = o;
}

// ---------------------------------------------------------------------------
extern "C" void kernel_launch(void* const* d_in, const int* in_sizes, int n_in,
                              void* d_out, int out_size, void* d_ws,
                              size_t ws_size, hipStream_t stream) {
  const float* x = (const float*)d_in[0];
  const float* tmx = (const float*)d_in[1];
  const float* tmw = (const float*)d_in[2];
  const float* tmk = (const float*)d_in[3];
  const float* tmv = (const float*)d_in[4];
  const float* tmr = (const float*)d_in[5];
  const float* maa_w1 = (const float*)d_in[6];
  const float* maa_w2 = (const float*)d_in[7];
  const float* decay_w1 = (const float*)d_in[8];
  const float* decay_w2 = (const float*)d_in[9];
  const float* time_decay = (const float*)d_in[10];
  const float* faaaa = (const float*)d_in[11];
  const float* Wr = (const float*)d_in[12];
  const float* Wk = (const float*)d_in[13];
  const float* Wv = (const float*)d_in[14];
  const float* Wo = (const float*)d_in[15];
  const float* lng = (const float*)d_in[16];
  const float* lnb = (const float*)d_in[17];
  float* out = (float*)d_out;
  float* ws = (float*)d_ws;

  const size_t S = (size_t)BT * CC;  // 8388608

  // f32 region
  float* y_ = ws;                     // attn out
  float* dw2r = ws + S;               // 1024
  float* tdr = dw2r + 1024;           // pad to 1024
  float* wlog = tdr + 1024;           // 131072
  float* cum = wlog + 131072;
  float* excl = cum + 131072;
  float* wsl = excl + 131072;         // pad to 1024
  float* diagG = wsl + 1024;          // 131072
  float* kvb = diagG + 131072;        // 512*4096
  float* stb = kvb + (size_t)512 * 4096;
  float* fend = stb + (size_t)512 * 4096;
  // bf16 region (u16)
  u16* xxxb = (u16*)fend;             // mix out -> maa GEMM in -> vT
  u16* mb = xxxb + S;                 // BT*128
  u16* xkb = mb + (size_t)BT * 128;   // blend out -> gemm_dp in -> ylnb
  u16* xvb = xkb + S;                 // blend out -> gemm_dp in
  u16* xrb = xvb + S;                 // blend out -> gemm_dp in
  u16* xwb = xrb + S;                 // blend out -> decay_mfma in
  u16* rb16 = xwb + S;                // gemm_dp out
  u16* kb16 = rb16 + S;               // gemm_dp out
  u16* Vb = kb16 + S;                 // gemm_dp out
  u16* Wrt = Vb + S;
  u16* Wkt = Wrt + (size_t)1024 * 1024;
  u16* Wvt = Wkt + (size_t)1024 * 1024;
  u16* Wot = Wvt + (size_t)1024 * 1024;
  u16* w1T = Wot + (size_t)1024 * 1024;   // [128][1024]
  u16* w2T = w1T + (size_t)128 * 1024;    // [1024][128]
  u16* d1T = w2T + (size_t)1024 * 128;    // [64][1024]
  u16* dw2rbT = d1T + (size_t)64 * 1024;  // [16][64]
  // aliases (stream-ordered reuse)
  u16* vT = xxxb;   // kvfuse writes, attn reads (after gemm_maa consumed xxxb)
  u16* ylnb = xkb;  // after gemm_dp consumed xkb

  // allow 72 KB dynamic LDS for the deep-pipelined GEMMs (once per process)
  static bool attr_done = false;
  if (!attr_done) {
    hipFuncSetAttribute((const void*)gemm_dp<true, false>,
                        hipFuncAttributeMaxDynamicSharedMemorySize, DP_SMEM_BYTES);
    hipFuncSetAttribute((const void*)gemm_dp<false, true>,
                        hipFuncAttributeMaxDynamicSharedMemorySize, DP_SMEM_BYTES);
    attr_done = true;
  }

  // merged weight prep (cvt_wT + cvt3_T + dw2r in one launch)
  cvt_all<<<dim3(16, 16, 8), 256, 0, stream>>>(
      Wr, Wk, Wv, Wo, Wrt, Wkt, Wvt, Wot, maa_w1, maa_w2, decay_w1, w1T, w2T,
      d1T, decay_w2, time_decay, dw2r, tdr, dw2rbT);
  mix_kernel<<<8192, 256, 0, stream>>>(x, tmx, xxxb);
  gemm_maa<<<dim3(2, 128), 256, 0, stream>>>(xxxb, w1T, mb);
  blend_mfma<<<dim3(16, 128), 256, 0, stream>>>(mb, w2T, x, tmw, tmk, tmv, tmr,
                                                xwb, xkb, xvb, xrb);
  decay_mfma<<<256, 256, 0, stream>>>(xwb, d1T, dw2rbT, tdr, wlog);
  wprep_kernel<<<512, 256, 0, stream>>>(wlog, cum, excl, wsl);
  // fused r/k/v projections: deep-pipelined GEMM v5b (BK=32, fixed swizzle)
  gemm_dp<true, false><<<dim3(4, 64, 3), 512, DP_SMEM_BYTES, stream>>>(
      xrb, xkb, xvb, Wrt, Wkt, Wvt, nullptr, rb16, kb16, Vb);
  // fused transpose + diag + kv
  kvfuse_kernel<<<512, 256, 0, stream>>>(Vb, kb16, rb16, faaaa, cum, wsl, vT,
                                         diagG, kvb);
  scan_kernel<<<256, 256, 0, stream>>>(kvb, wsl, stb);
  attn_mfma<<<512, 256, 0, stream>>>(rb16, kb16, vT, stb, cum, excl, diagG, y_);
  ln_kernel<<<BT, 256, 0, stream>>>(y_, lng, lnb, ylnb);
  // output projection: same deep-pipelined GEMM, f32 out
  gemm_dp<false, true><<<dim3(4, 64, 1), 512, DP_SMEM_BYTES, stream>>>(
      ylnb, nullptr, nullptr, Wot, nullptr, nullptr, out, nullptr, nullptr,
      nullptr);
}

// Round 12
// 320.783 us; speedup vs baseline: 1.0950x; 1.0812x over previous
//
#include <hip/hip_runtime.h>
#include <math.h>

// B=4, T=2048, C=1024, H=16, N=64, Q=256, nc=8, BT=8192
#define BB 4
#define TT 2048
#define CC 1024
#define HH 16
#define NN 64
#define QQ 256
#define NCH 8
#define BT 8192

typedef unsigned short u16;
typedef __attribute__((ext_vector_type(8))) short bf16x8;
typedef __attribute__((ext_vector_type(4))) short bf16x4;
typedef __attribute__((ext_vector_type(4))) float f32x4;
typedef __attribute__((ext_vector_type(4))) u16 u16x4;

// f32 -> bf16 bits, round-to-nearest-even
__device__ inline u16 f2b(float x) {
  union { float f; unsigned u; } v;
  v.f = x;
  unsigned r = v.u + 0x7FFFu + ((v.u >> 16) & 1u);
  return (u16)(r >> 16);
}
__device__ inline float b2f(u16 u) {
  union { unsigned u; float f; } v;
  v.u = ((unsigned)u) << 16;
  return v.f;
}
// 16B fragment from padded LDS row via two 8B loads (conflict-friendly)
__device__ inline bf16x8 ldfrag(const u16* p) {
  bf16x4 lo = *(const bf16x4*)p;
  bf16x4 hi = *(const bf16x4*)(p + 4);
  return __builtin_shufflevector(lo, hi, 0, 1, 2, 3, 4, 5, 6, 7);
}
// stage 64x64 bf16 tile (global pitch `pitch` u16) into LDS stride-72
__device__ inline void stage_tile(const u16* __restrict__ g, size_t base,
                                  int pitch, int tid, u16* __restrict__ lds) {
#pragma unroll
  for (int it = 0; it < 2; it++) {
    int cidx = tid + it * 256;  // 0..511
    int r = cidx >> 3, c8 = (cidx & 7) * 8;
    bf16x8 v = *(const bf16x8*)(g + base + (size_t)r * pitch + c8);
    *(bf16x4*)(lds + r * 72 + c8) = __builtin_shufflevector(v, v, 0, 1, 2, 3);
    *(bf16x4*)(lds + r * 72 + c8 + 4) = __builtin_shufflevector(v, v, 4, 5, 6, 7);
  }
}

// ---------------------------------------------------------------------------
// 1. time-shift mix: xxx -> bf16, 8 elems/thread (16B load/store), grid 4096
// ---------------------------------------------------------------------------
__global__ __launch_bounds__(256) void mix_kernel(const float* __restrict__ x,
                                                  const float* __restrict__ tmx,
                                                  u16* __restrict__ xxxb) {
  size_t e = ((size_t)blockIdx.x * 256 + threadIdx.x) * 8;
  int c = (int)(e & 1023);
  size_t row = e >> 10;
  int t = (int)(row & 2047);
  float4 xa = *(const float4*)(x + e);
  float4 xb = *(const float4*)(x + e + 4);
  float4 pa = make_float4(0.f, 0.f, 0.f, 0.f);
  float4 pb = make_float4(0.f, 0.f, 0.f, 0.f);
  if (t > 0) {
    pa = *(const float4*)(x + e - 1024);
    pb = *(const float4*)(x + e - 1020);
  }
  float4 ta = *(const float4*)(tmx + c);
  float4 tb = *(const float4*)(tmx + c + 4);
  u16x4 oa, ob;
  oa.x = f2b(xa.x + (pa.x - xa.x) * ta.x);
  oa.y = f2b(xa.y + (pa.y - xa.y) * ta.y);
  oa.z = f2b(xa.z + (pa.z - xa.z) * ta.z);
  oa.w = f2b(xa.w + (pa.w - xa.w) * ta.w);
  ob.x = f2b(xb.x + (pb.x - xb.x) * tb.x);
  ob.y = f2b(xb.y + (pb.y - xb.y) * tb.y);
  ob.z = f2b(xb.z + (pb.z - xb.z) * tb.z);
  ob.w = f2b(xb.w + (pb.w - xb.w) * tb.w);
  *(u16x4*)(xxxb + e) = oa;
  *(u16x4*)(xxxb + e + 4) = ob;
}

// ---------------------------------------------------------------------------
// merged weight prep (ONE launch), grid (16,16,8):
//   z<4 : big 1024x1024 weight f32[k][n] -> bf16 Wt[n][k]
//   z=4 : maa_w1 f32[1024][128] -> w1T bf16[128][1024]
//   z=5 : maa_w2 f32[128][1024] -> w2T bf16[1024][128]
//   z=6 : decay_w1 f32[1024][64] -> d1T bf16[64][1024]
//   z=7 : dw2r reduce (blocks x<4, y==0 only)
// out-of-range tiles return immediately.
// ---------------------------------------------------------------------------
__global__ __launch_bounds__(256) void cvt_all(
    const float* __restrict__ W0, const float* __restrict__ W1,
    const float* __restrict__ W2, const float* __restrict__ W3,
    u16* __restrict__ O0, u16* __restrict__ O1, u16* __restrict__ O2,
    u16* __restrict__ O3, const float* __restrict__ w1,
    const float* __restrict__ w2, const float* __restrict__ d1,
    u16* __restrict__ o1, u16* __restrict__ o2, u16* __restrict__ o3,
    const float* __restrict__ dw2, const float* __restrict__ td,
    float* __restrict__ dw2r, float* __restrict__ tdr,
    u16* __restrict__ dw2rbT) {
  int z = blockIdx.z;
  if (z == 7) {
    if (blockIdx.y != 0 || blockIdx.x >= 4) return;
    int idx = blockIdx.x * 256 + threadIdx.x;
    if (idx < 1024) {
      int j = idx >> 4, h = idx & 15;
      float s = 0.f;
      for (int n = 0; n < 64; n++) s += dw2[(size_t)j * 1024 + h * 64 + n];
      float m = s * (1.f / 64.f);
      dw2r[j * 16 + h] = m;
      dw2rbT[h * 64 + j] = f2b(m);
    }
    if (idx < 16) {
      float s = 0.f;
      for (int n = 0; n < 64; n++) s += td[idx * 64 + n];
      tdr[idx] = s * (1.f / 64.f);
    }
    return;
  }
  const float* in;
  u16* out;
  int R, C;
  switch (z) {
    case 0: in = W0; out = O0; R = 1024; C = 1024; break;
    case 1: in = W1; out = O1; R = 1024; C = 1024; break;
    case 2: in = W2; out = O2; R = 1024; C = 1024; break;
    case 3: in = W3; out = O3; R = 1024; C = 1024; break;
    case 4: in = w1; out = o1; R = 1024; C = 128; break;
    case 5: in = w2; out = o2; R = 128; C = 1024; break;
    default: in = d1; out = o3; R = 1024; C = 64; break;
  }
  int c0 = blockIdx.x * 64, r0 = blockIdx.y * 64;
  if (c0 >= C || r0 >= R) return;
  __shared__ float t[64][65];
#pragma unroll
  for (int it = 0; it < 16; it++) {
    int idx = it * 256 + threadIdx.x;
    int r = idx >> 6, c = idx & 63;
    t[r][c] = in[(size_t)(r0 + r) * C + c0 + c];
  }
  __syncthreads();
#pragma unroll
  for (int it = 0; it < 16; it++) {
    int idx = it * 256 + threadIdx.x;
    int c = idx >> 6, r = idx & 63;
    out[(size_t)(c0 + c) * R + r0 + r] = f2b(t[r][c]);
  }
}

// ---------------------------------------------------------------------------
// maa GEMM: mb = tanh(xxx @ w1) : A[8192][1024] x w1T[128][1024] -> [8192][128]
// 64x64 tiles -> grid (2,128) = 256 blocks (full-CU coverage).
// ---------------------------------------------------------------------------
__global__ __launch_bounds__(256) void gemm_maa(const u16* __restrict__ A,
                                                const u16* __restrict__ Bt,
                                                u16* __restrict__ Cb) {
  __shared__ u16 As[64 * 32];
  __shared__ u16 Bs[64 * 32];
  const int tid = threadIdx.x;
  const int lane = tid & 63;
  const int wave = tid >> 6;
  const int wc = wave * 16;
  const int fr = lane & 15;
  const int fq = lane >> 4;
  const int row0 = blockIdx.y * 64;
  const int col0 = blockIdx.x * 64;

  f32x4 acc[4];
#pragma unroll
  for (int i = 0; i < 4; i++) acc[i] = (f32x4){0.f, 0.f, 0.f, 0.f};

  const int ra = tid >> 2, ca = (tid & 3) * 8;

  for (int k0 = 0; k0 < 1024; k0 += 32) {
    __builtin_amdgcn_global_load_lds(
        (const __attribute__((address_space(1))) void*)(A + (size_t)(row0 + ra) * 1024 + k0 + ca),
        (__attribute__((address_space(3))) void*)(As + tid * 8), 16, 0, 0);
    __builtin_amdgcn_global_load_lds(
        (const __attribute__((address_space(1))) void*)(Bt + (size_t)(col0 + ra) * 1024 + k0 + ca),
        (__attribute__((address_space(3))) void*)(Bs + tid * 8), 16, 0, 0);
    __syncthreads();
    bf16x8 bf = *(const bf16x8*)(Bs + ((wc + fr) * 32 + fq * 8));
#pragma unroll
    for (int i = 0; i < 4; i++) {
      bf16x8 af = *(const bf16x8*)(As + ((i * 16 + fr) * 32 + fq * 8));
      acc[i] = __builtin_amdgcn_mfma_f32_16x16x32_bf16(af, bf, acc[i], 0, 0, 0);
    }
    __syncthreads();
  }
#pragma unroll
  for (int i = 0; i < 4; i++) {
    int grow = row0 + i * 16 + fq * 4;
#pragma unroll
    for (int r = 0; r < 4; r++)
      Cb[(size_t)(grow + r) * 128 + col0 + wc + fr] = f2b(tanhf(acc[i][r]));
  }
}

// ---------------------------------------------------------------------------
// Deep-pipelined bf16 GEMM v5b: M=8192, N=1024, K=1024.
// BM=128 x BN=256 x BK=32, 512 threads (8 waves, 64x64 wave tiles).
// 3 LDS buffers x 24 KB = 72 KB -> 2 blocks/CU. Depth-2 prefetch, counted
// vmcnt(3), raw s_barrier (1 per K-tile, 32 tiles).
// Swizzle: s(row) = (row>>1)&3 both sides (bank-conflict-free, R11: 0 confl).
// grid (4, 64, gz); nwg % 8 == 0; bijective XCD swizzle.
// ---------------------------------------------------------------------------
#define DP_ABUF 4096    /* u16: 128*32 */
#define DP_BBUF 8192    /* u16: 256*32 */
#define DP_SBUF 12288   /* u16 per buffer (24 KB) */
#define DP_SMEM_BYTES 73728 /* 3 buffers = 72 KB */

template <bool TRIPLE, bool F32OUT>
__global__ __launch_bounds__(512, 2) void gemm_dp(
    const u16* __restrict__ A0, const u16* __restrict__ A1,
    const u16* __restrict__ A2, const u16* __restrict__ B0,
    const u16* __restrict__ B1, const u16* __restrict__ B2,
    float* __restrict__ Cf, u16* __restrict__ C0, u16* __restrict__ C1,
    u16* __restrict__ C2) {
  extern __shared__ __align__(16) u16 smem[];
  // T1: bijective XCD swizzle over flattened grid (x fastest; gridDim=(4,64,z))
  const int nwg = (int)(gridDim.x * gridDim.y * gridDim.z);
  const int wg = (int)(blockIdx.x + (blockIdx.y << 2) + (blockIdx.z << 8));
  const int cpx = nwg >> 3;
  const int swz = (wg & 7) * cpx + (wg >> 3);
  const int bx = swz & 3;
  const int by = (swz >> 2) & 63;
  const int bz = swz >> 8;

  const u16* __restrict__ A;
  const u16* __restrict__ Bt;
  u16* __restrict__ Cb;
  if (TRIPLE) {
    switch (bz) {
      case 0: A = A0; Bt = B0; Cb = C0; break;
      case 1: A = A1; Bt = B1; Cb = C1; break;
      default: A = A2; Bt = B2; Cb = C2; break;
    }
  } else {
    A = A0; Bt = B0; Cb = C0;
  }

  const int tid = threadIdx.x;
  const int lane = tid & 63;
  const int wave = tid >> 6;        // 0..7
  const int wr = (wave >> 2) * 64;  // 0 / 64
  const int wc = (wave & 3) * 64;   // 0 / 64 / 128 / 192
  const int fr = lane & 15;
  const int fq = lane >> 4;
  const int s4 = (fr >> 1) & 3;     // == (frag row >> 1) & 3
  const int row0 = by * 128;
  const int col0 = bx * 256;

  // per-lane LDS frag offsets (u16 units), loop-invariant; single K-slice
  int aoff[4], boff[4];
#pragma unroll
  for (int mi = 0; mi < 4; mi++)
    aoff[mi] = (wr + mi * 16 + fr) * 32 + ((fq ^ s4) * 8);
#pragma unroll
  for (int nj = 0; nj < 4; nj++)
    boff[nj] = (wc + nj * 16 + fr) * 32 + ((fq ^ s4) * 8);

  // stage tile kt (3 x 16B per thread: A 1, B 2) into buffer q; global source
  // pre-swizzled so linear LDS dest + swizzled read = consistent involution.
  auto stage = [&](int kt, int q) {
    const u16* __restrict__ gA = A + (size_t)row0 * 1024 + kt * 32;
    const u16* __restrict__ gB = Bt + (size_t)col0 * 1024 + kt * 32;
    u16* dA = smem + q * DP_SBUF;
    u16* dB = dA + DP_ABUF;
    {
      int pos = tid;                    // 0..511 (A: 128 rows x 4 chunks)
      int r = pos >> 2, gch = (pos & 3) ^ ((r >> 1) & 3);
      __builtin_amdgcn_global_load_lds(
          (const __attribute__((address_space(1))) void*)(gA + (size_t)r * 1024 + gch * 8),
          (__attribute__((address_space(3))) void*)(dA + pos * 8), 16, 0, 0);
    }
#pragma unroll
    for (int p = 0; p < 2; p++) {
      int pos = tid + p * 512;          // 0..1023 (B: 256 rows x 4 chunks)
      int r = pos >> 2, gch = (pos & 3) ^ ((r >> 1) & 3);
      __builtin_amdgcn_global_load_lds(
          (const __attribute__((address_space(1))) void*)(gB + (size_t)r * 1024 + gch * 8),
          (__attribute__((address_space(3))) void*)(dB + pos * 8), 16, 0, 0);
    }
  };

  f32x4 acc[4][4];
#pragma unroll
  for (int mi = 0; mi < 4; mi++)
#pragma unroll
    for (int nj = 0; nj < 4; nj++) acc[mi][nj] = (f32x4){0.f, 0.f, 0.f, 0.f};

  auto iter_body = [&](int qc, int qs, bool dostage, int t2) {
    if (dostage) stage(t2, qs);  // issue next+1 tile loads early
    const u16* sA = smem + qc * DP_SBUF;
    const u16* sB = sA + DP_ABUF;
    bf16x8 av[4], bv[4];
#pragma unroll
    for (int mi = 0; mi < 4; mi++) av[mi] = *(const bf16x8*)(sA + aoff[mi]);
#pragma unroll
    for (int nj = 0; nj < 4; nj++) bv[nj] = *(const bf16x8*)(sB + boff[nj]);
    __builtin_amdgcn_s_setprio(1);
#pragma unroll
    for (int mi = 0; mi < 4; mi++)
#pragma unroll
      for (int nj = 0; nj < 4; nj++)
        acc[mi][nj] = __builtin_amdgcn_mfma_f32_16x16x32_bf16(
            av[mi], bv[nj], acc[mi][nj], 0, 0, 0);
    __builtin_amdgcn_s_setprio(0);
  };

  // prologue: 2 tiles in flight (6 loads)
  stage(0, 0);
  stage(1, 1);
  int qc = 0, qs = 2;
  // main loop: wait current tile (vmcnt 3: leaves next tile's 3 in flight)
  for (int t = 0; t < 30; t++) {
    asm volatile("s_waitcnt vmcnt(3)" ::: "memory");
    __builtin_amdgcn_s_barrier();
    iter_body(qc, qs, true, t + 2);
    qc = (qc == 2) ? 0 : qc + 1;
    qs = (qs == 2) ? 0 : qs + 1;
  }
  // t = 30: no more staging; tile 31's 3 loads remain in flight
  asm volatile("s_waitcnt vmcnt(3)" ::: "memory");
  __builtin_amdgcn_s_barrier();
  iter_body(qc, 0, false, 0);
  qc = (qc == 2) ? 0 : qc + 1;
  // t = 31: drain
  asm volatile("s_waitcnt vmcnt(0)" ::: "memory");
  __builtin_amdgcn_s_barrier();
  iter_body(qc, 0, false, 0);

#pragma unroll
  for (int mi = 0; mi < 4; mi++) {
    int grow = row0 + wr + mi * 16 + fq * 4;
#pragma unroll
    for (int nj = 0; nj < 4; nj++) {
      int gcol = col0 + wc + nj * 16 + fr;
#pragma unroll
      for (int r = 0; r < 4; r++) {
        if (F32OUT)
          Cf[(size_t)(grow + r) * 1024 + gcol] = acc[mi][nj][r];
        else
          Cb[(size_t)(grow + r) * 1024 + gcol] = f2b(acc[mi][nj][r]);
      }
    }
  }
}

// ---------------------------------------------------------------------------
// 3. blend via MFMA (fused x/xx/tm* epilogue); xx recomputed inline from x.
// ---------------------------------------------------------------------------
__global__ __launch_bounds__(256) void blend_mfma(
    const u16* __restrict__ mb, const u16* __restrict__ w2T,
    const float* __restrict__ x,
    const float* __restrict__ tmw, const float* __restrict__ tmk,
    const float* __restrict__ tmv, const float* __restrict__ tmr,
    u16* __restrict__ xwb, u16* __restrict__ xkb, u16* __restrict__ xvb,
    u16* __restrict__ xrb) {
  __shared__ u16 mS[64 * 136];
  __shared__ u16 wS[64 * 136];
  const int tid = threadIdx.x;
  const int lane = tid & 63;
  const int w = tid >> 6;
  const int fr = lane & 15;
  const int fq = lane >> 4;
  const int c0 = blockIdx.x * 64;
  const int bt0 = blockIdx.y * 64;

#pragma unroll
  for (int it = 0; it < 4; it++) {
    int idx = tid + it * 256;  // 0..1023
    int r = idx >> 4, c8 = (idx & 15) * 8;
    bf16x8 v = *(const bf16x8*)(mb + (size_t)(bt0 + r) * 128 + c8);
    *(bf16x4*)(mS + r * 136 + c8) = __builtin_shufflevector(v, v, 0, 1, 2, 3);
    *(bf16x4*)(mS + r * 136 + c8 + 4) = __builtin_shufflevector(v, v, 4, 5, 6, 7);
    bf16x8 u = *(const bf16x8*)(w2T + (size_t)(c0 + r) * 128 + c8);
    *(bf16x4*)(wS + r * 136 + c8) = __builtin_shufflevector(u, u, 0, 1, 2, 3);
    *(bf16x4*)(wS + r * 136 + c8 + 4) = __builtin_shufflevector(u, u, 4, 5, 6, 7);
  }
  __syncthreads();

  f32x4 acc[4][4];  // [col-tile j][f]
#pragma unroll
  for (int j = 0; j < 4; j++)
#pragma unroll
    for (int f = 0; f < 4; f++) acc[j][f] = (f32x4){0.f, 0.f, 0.f, 0.f};

#pragma unroll
  for (int f = 0; f < 4; f++) {
    bf16x8 aA = ldfrag(mS + (w * 16 + fr) * 136 + f * 32 + fq * 8);
#pragma unroll
    for (int j = 0; j < 4; j++) {
      bf16x8 bB = ldfrag(wS + (j * 16 + fr) * 136 + f * 32 + fq * 8);
      acc[j][f] = __builtin_amdgcn_mfma_f32_16x16x32_bf16(aA, bB, acc[j][f], 0, 0, 0);
    }
  }

#pragma unroll
  for (int j = 0; j < 4; j++) {
    int c = c0 + j * 16 + fr;
    float w_ = tmw[c], k_ = tmk[c], v_ = tmv[c], r_ = tmr[c];
#pragma unroll
    for (int rr = 0; rr < 4; rr++) {
      int bt = bt0 + w * 16 + fq * 4 + rr;
      size_t g = (size_t)bt * 1024 + c;
      float xv_ = x[g];
      float xp = ((bt & 2047) != 0) ? x[g - 1024] : 0.f;
      float dx = xp - xv_;
      xwb[g] = f2b(xv_ + dx * (w_ + acc[j][0][rr]));
      xkb[g] = f2b(xv_ + dx * (k_ + acc[j][1][rr]));
      xvb[g] = f2b(xv_ + dx * (v_ + acc[j][2][rr]));
      xrb[g] = f2b(xv_ + dx * (r_ + acc[j][3][rr]));
    }
  }
}

// ---------------------------------------------------------------------------
// 5b. fused decay GEMM: h1 = tanh(xw @ d1) via MFMA (K=1024), then
//     wlog = -exp(tdr + h1 @ dw2r). 32-row tiles -> 256 blocks.
// ---------------------------------------------------------------------------
__global__ __launch_bounds__(256) void decay_mfma(const u16* __restrict__ xwb,
                                                  const u16* __restrict__ d1T,
                                                  const u16* __restrict__ dw2rbT,
                                                  const float* __restrict__ tdr,
                                                  float* __restrict__ wlog) {
  __shared__ u16 As[32 * 64];
  __shared__ u16 Bs[64 * 64];
  __shared__ u16 h1S[32 * 72];
  __shared__ u16 dwS[16 * 72];
  const int tid = threadIdx.x;
  const int lane = tid & 63;
  const int w = tid >> 6;
  const int fr = lane & 15;
  const int fq = lane >> 4;
  const int s8 = fr & 7;
  const int bt0 = blockIdx.x * 32;

#pragma unroll
  for (int it = 0; it < 4; it++) {
    int idx = tid + it * 256;
    int r = idx >> 6, c = idx & 63;
    dwS[r * 72 + c] = dw2rbT[r * 64 + c];
  }

  f32x4 acc[2];
#pragma unroll
  for (int mi = 0; mi < 2; mi++) acc[mi] = (f32x4){0.f, 0.f, 0.f, 0.f};

  const int raA = tid >> 3;              // 0..31
  const int gchA = (tid & 7) ^ (raA & 7);

  for (int k0 = 0; k0 < 1024; k0 += 64) {
    __builtin_amdgcn_global_load_lds(
        (const __attribute__((address_space(1))) void*)(
            xwb + (size_t)(bt0 + raA) * 1024 + k0 + gchA * 8),
        (__attribute__((address_space(3))) void*)(As + tid * 8), 16, 0, 0);
#pragma unroll
    for (int p = 0; p < 2; p++) {
      int pos = tid + p * 256;           // 0..511
      int r = pos >> 3, gch = (pos & 7) ^ (r & 7);
      __builtin_amdgcn_global_load_lds(
          (const __attribute__((address_space(1))) void*)(
              d1T + (size_t)r * 1024 + k0 + gch * 8),
          (__attribute__((address_space(3))) void*)(Bs + pos * 8), 16, 0, 0);
    }
    __syncthreads();
#pragma unroll
    for (int ks = 0; ks < 2; ks++) {
      int chunk = ((ks * 4 + fq) ^ s8) * 8;
      bf16x8 bB = *(const bf16x8*)(Bs + (w * 16 + fr) * 64 + chunk);
#pragma unroll
      for (int mi = 0; mi < 2; mi++) {
        bf16x8 aA = *(const bf16x8*)(As + (mi * 16 + fr) * 64 + chunk);
        acc[mi] = __builtin_amdgcn_mfma_f32_16x16x32_bf16(aA, bB, acc[mi], 0, 0, 0);
      }
    }
    __syncthreads();
  }
#pragma unroll
  for (int mi = 0; mi < 2; mi++)
#pragma unroll
    for (int rr = 0; rr < 4; rr++)
      h1S[(mi * 16 + fq * 4 + rr) * 72 + w * 16 + fr] = f2b(tanhf(acc[mi][rr]));
  __syncthreads();

  if (w < 2) {
    f32x4 a2 = (f32x4){0.f, 0.f, 0.f, 0.f};
#pragma unroll
    for (int ks = 0; ks < 2; ks++) {
      bf16x8 aA = ldfrag(h1S + (w * 16 + fr) * 72 + ks * 32 + fq * 8);
      bf16x8 bB = ldfrag(dwS + fr * 72 + ks * 32 + fq * 8);
      a2 = __builtin_amdgcn_mfma_f32_16x16x32_bf16(aA, bB, a2, 0, 0, 0);
    }
    float tdv = tdr[fr];
#pragma unroll
    for (int rr = 0; rr < 4; rr++) {
      int bt = bt0 + w * 16 + fq * 4 + rr;
      int b = bt >> 11, tl = bt & 2047;
      wlog[((size_t)(b * 16 + fr)) * 2048 + tl] = -__expf(tdv + a2[rr]);
    }
  }
}

// ---------------------------------------------------------------------------
// 7. per-chunk scan
// ---------------------------------------------------------------------------
__global__ __launch_bounds__(256) void wprep_kernel(const float* __restrict__ wlog,
                                                    float* __restrict__ cum,
                                                    float* __restrict__ excl,
                                                    float* __restrict__ wsl) {
  int bid = blockIdx.x;
  int c = bid & 7, bh = bid >> 3;
  int q = threadIdx.x;
  float v = wlog[(size_t)bh * 2048 + c * 256 + q];
  __shared__ float s[256];
  s[q] = v;
  float val = v;
  for (int off = 1; off < 256; off <<= 1) {
    __syncthreads();
    float t = (q >= off) ? s[q - off] : 0.f;
    __syncthreads();
    val += t;
    s[q] = val;
  }
  __syncthreads();
  float total = s[255];
  cum[(size_t)bid * 256 + q] = val;
  excl[(size_t)bid * 256 + q] = val - v;
  if (q == 0) wsl[bid] = total;
}

// ---------------------------------------------------------------------------
// kvfuse v2: per (bh, chunk) block — VECTORIZED transpose + diag + kv.
//  - global loads bf16x8 (16B): 2 iterations/qt (was 16 scalar-u16 iters)
//  - diag: per-thread 8-elem local sum + 3-shfl reduce across the 8 aligned
//    lanes sharing a row (was 6 shfl x 16 iters)
//  - write-out: u16x4-pair (16B) stores to vT / vSb / kSb: 2 iterations/qt
// LDS tv/tk layout, wfac math, MFMA phase and barrier structure unchanged.
// ---------------------------------------------------------------------------
__global__ __launch_bounds__(256) void kvfuse_kernel(
    const u16* __restrict__ vb, const u16* __restrict__ kb,
    const u16* __restrict__ rb, const float* __restrict__ faaaa,
    const float* __restrict__ cum, const float* __restrict__ wsl,
    u16* __restrict__ vT, float* __restrict__ diagG, float* __restrict__ kvb) {
  int bid = blockIdx.x;
  int c = bid & 7, bh = bid >> 3;
  int b = bh >> 4, h = bh & 15;
  __shared__ float tv[64][65];
  __shared__ float tk[64][65];
  __shared__ u16 kSb[64 * 72];
  __shared__ u16 vSb[64 * 72];
  __shared__ float wfacS[256];
  __shared__ float faS[64];
  const int tid = threadIdx.x;
  const int lane = tid & 63;
  const int w = tid >> 6;
  const int fr = lane & 15;
  const int fq = lane >> 4;

  float wslog = wsl[bid];
  wfacS[tid] = __expf(wslog - cum[(size_t)bid * 256 + tid]);
  if (tid < 64) faS[tid] = faaaa[h * 64 + tid];

  f32x4 acc[4];
#pragma unroll
  for (int j = 0; j < 4; j++) acc[j] = (f32x4){0.f, 0.f, 0.f, 0.f};

  for (int qt = 0; qt < 4; qt++) {
    __syncthreads();  // tv/tk free (prev write-out done); wfacS/faS ready
    int t0 = c * QQ + qt * 64;
    // ---- vectorized load + transpose-to-LDS + diag ----
#pragma unroll
    for (int it2 = 0; it2 < 2; it2++) {
      int idx2 = it2 * 256 + tid;       // 0..511
      int r = idx2 >> 3, cg = (idx2 & 7) * 8;
      size_t g = ((size_t)(b * TT + t0 + r)) * CC + h * 64 + cg;
      bf16x8 v8 = *(const bf16x8*)(vb + g);
      bf16x8 k8 = *(const bf16x8*)(kb + g);
      bf16x8 r8 = *(const bf16x8*)(rb + g);
      float s = 0.f;
#pragma unroll
      for (int j = 0; j < 8; j++) {
        float vf = b2f((u16)v8[j]);
        float kf = b2f((u16)k8[j]);
        float rf = b2f((u16)r8[j]);
        tv[r][cg + j] = vf;
        tk[r][cg + j] = kf;
        s += rf * faS[cg + j] * kf;
      }
      // 8 consecutive lanes (aligned) share row r -> 3-shfl reduce
      s += __shfl_xor(s, 1);
      s += __shfl_xor(s, 2);
      s += __shfl_xor(s, 4);
      if ((idx2 & 7) == 0) diagG[(size_t)bh * 2048 + t0 + r] = s;
    }
    __syncthreads();
    // ---- vectorized write-out: vT + vSb + kSb ----
#pragma unroll
    for (int it = 0; it < 2; it++) {
      int idx = it * 256 + tid;         // 0..511
      int mm = idx >> 3, tg = (idx & 7) * 8;
      u16x4 va, vb4, ka, kb4;
      va.x = f2b(tv[tg + 0][mm]);
      va.y = f2b(tv[tg + 1][mm]);
      va.z = f2b(tv[tg + 2][mm]);
      va.w = f2b(tv[tg + 3][mm]);
      vb4.x = f2b(tv[tg + 4][mm]);
      vb4.y = f2b(tv[tg + 5][mm]);
      vb4.z = f2b(tv[tg + 6][mm]);
      vb4.w = f2b(tv[tg + 7][mm]);
      ka.x = f2b(tk[tg + 0][mm] * wfacS[qt * 64 + tg + 0]);
      ka.y = f2b(tk[tg + 1][mm] * wfacS[qt * 64 + tg + 1]);
      ka.z = f2b(tk[tg + 2][mm] * wfacS[qt * 64 + tg + 2]);
      ka.w = f2b(tk[tg + 3][mm] * wfacS[qt * 64 + tg + 3]);
      kb4.x = f2b(tk[tg + 4][mm] * wfacS[qt * 64 + tg + 4]);
      kb4.y = f2b(tk[tg + 5][mm] * wfacS[qt * 64 + tg + 5]);
      kb4.z = f2b(tk[tg + 6][mm] * wfacS[qt * 64 + tg + 6]);
      kb4.w = f2b(tk[tg + 7][mm] * wfacS[qt * 64 + tg + 7]);
      size_t o = ((size_t)(bh * 64 + mm)) * TT + t0 + tg;
      *(u16x4*)(vT + o) = va;
      *(u16x4*)(vT + o + 4) = vb4;
      *(u16x4*)(vSb + mm * 72 + tg) = va;
      *(u16x4*)(vSb + mm * 72 + tg + 4) = vb4;
      *(u16x4*)(kSb + mm * 72 + tg) = ka;
      *(u16x4*)(kSb + mm * 72 + tg + 4) = kb4;
    }
    __syncthreads();
    // ---- kv MFMA (unchanged) ----
#pragma unroll
    for (int ks = 0; ks < 2; ks++) {
      bf16x8 aA = ldfrag(kSb + (w * 16 + fr) * 72 + ks * 32 + fq * 8);
#pragma unroll
      for (int j = 0; j < 4; j++) {
        bf16x8 bB = ldfrag(vSb + (j * 16 + fr) * 72 + ks * 32 + fq * 8);
        acc[j] = __builtin_amdgcn_mfma_f32_16x16x32_bf16(aA, bB, acc[j], 0, 0, 0);
      }
    }
  }
#pragma unroll
  for (int j = 0; j < 4; j++)
#pragma unroll
    for (int rr = 0; rr < 4; rr++)
      kvb[(size_t)bid * 4096 + (w * 16 + fq * 4 + rr) * 64 + j * 16 + fr] = acc[j][rr];
}

// ---------------------------------------------------------------------------
// 8b. sequential state scan over chunks — 256 blocks (bh x 4 slices), float4
// ---------------------------------------------------------------------------
__global__ __launch_bounds__(256) void scan_kernel(const float* __restrict__ kvb,
                                                   const float* __restrict__ wsl,
                                                   float* __restrict__ st) {
  int bh = blockIdx.x >> 2;
  int sl = blockIdx.x & 3;
  int tid = threadIdx.x;
  f32x4 s = (f32x4){0.f, 0.f, 0.f, 0.f};
  for (int c = 0; c < 8; c++) {
    int bid = bh * 8 + c;
    float w = __expf(wsl[bid]);
    size_t e = (size_t)bid * 4096 + sl * 1024 + tid * 4;
    f32x4 kv = *(const f32x4*)(kvb + e);
    *(f32x4*)(st + e) = s;
    s = w * s + kv;
  }
}

// ---------------------------------------------------------------------------
// 9. MFMA fused attention — qt-PAIR blocking (R9 structure, best measured).
// ---------------------------------------------------------------------------
__global__ __launch_bounds__(256) void attn_mfma(
    const u16* __restrict__ rb, const u16* __restrict__ kb,
    const u16* __restrict__ vT, const float* __restrict__ stg,
    const float* __restrict__ cum, const float* __restrict__ excl,
    const float* __restrict__ diagG, float* __restrict__ y) {
  int bid = blockIdx.x;
  int c = bid & 7, bh = bid >> 3;
  int b = bh >> 4, h = bh & 15;
  __shared__ u16 rt[64 * 72];
  __shared__ u16 kt[64 * 72];
  __shared__ u16 vt[64 * 72];
  __shared__ u16 pt[64 * 72];
  __shared__ u16 stT[64 * 72];
  __shared__ float cumS[256], exS[256], diagS[256], ekS[256];

  const int tid = threadIdx.x;
  const int lane = tid & 63;
  const int w = tid >> 6;
  const int fr = lane & 15;
  const int fq = lane >> 4;

  cumS[tid] = cum[(size_t)bid * 256 + tid];
  exS[tid] = excl[(size_t)bid * 256 + tid];
  diagS[tid] = diagG[(size_t)bh * 2048 + c * 256 + tid];
#pragma unroll
  for (int it = 0; it < 16; it++) {
    int idx = tid + it * 256;
    int n = idx >> 6, mm = idx & 63;
    stT[mm * 72 + n] = f2b(stg[(size_t)bid * 4096 + idx]);
  }
  __syncthreads();
  const float ccm = cumS[127];
  ekS[tid] = __expf(ccm - cumS[tid]);

  const size_t rowbase = ((size_t)b * TT + c * QQ) * CC + h * 64;
  const size_t vbase0 = (size_t)bh * 64 * TT + c * QQ;
  const int ql0 = w * 16 + fq * 4;

#pragma unroll
  for (int p = 0; p < 2; p++) {
    __syncthreads();  // prev pair's pt/kt/vt reads complete (p=1); noop-safe p=0
    stage_tile(rb, rowbase + (size_t)((2 * p) * 64) * CC, CC, tid, rt);
    stage_tile(rb, rowbase + (size_t)((2 * p + 1) * 64) * CC, CC, tid, pt);
    __syncthreads();
    bf16x8 rA[2][2];
    rA[0][0] = ldfrag(rt + (w * 16 + fr) * 72 + fq * 8);
    rA[0][1] = ldfrag(rt + (w * 16 + fr) * 72 + 32 + fq * 8);
    rA[1][0] = ldfrag(pt + (w * 16 + fr) * 72 + fq * 8);
    rA[1][1] = ldfrag(pt + (w * 16 + fr) * 72 + 32 + fq * 8);

    f32x4 acc[2][4];
    float eqc[2][4];
#pragma unroll
    for (int j = 0; j < 2; j++) {
      int qt = 2 * p + j;
#pragma unroll
      for (int jm = 0; jm < 4; jm++) acc[j][jm] = (f32x4){0.f, 0.f, 0.f, 0.f};
#pragma unroll
      for (int ks = 0; ks < 2; ks++)
#pragma unroll
        for (int jm = 0; jm < 4; jm++) {
          bf16x8 bB = ldfrag(stT + (jm * 16 + fr) * 72 + ks * 32 + fq * 8);
          acc[j][jm] = __builtin_amdgcn_mfma_f32_16x16x32_bf16(
              rA[j][ks], bB, acc[j][jm], 0, 0, 0);
        }
      float er[4];
#pragma unroll
      for (int rr = 0; rr < 4; rr++) {
        float ex = exS[qt * 64 + ql0 + rr];
        er[rr] = __expf(ex);
        eqc[j][rr] = __expf(ex - ccm);
      }
#pragma unroll
      for (int jm = 0; jm < 4; jm++)
#pragma unroll
        for (int rr = 0; rr < 4; rr++) acc[j][jm][rr] *= er[rr];
    }

#pragma unroll
    for (int kti = 0; kti < 2 * p + 2; kti++) {
      __syncthreads();  // rA[1] frag reads (kti=0) / prev PV pt reads done
      stage_tile(kb, rowbase + (size_t)(kti * 64) * CC, CC, tid, kt);
      stage_tile(vT, vbase0 + (size_t)(kti * 64), TT, tid, vt);
      __syncthreads();
#pragma unroll
      for (int j = 0; j < 2; j++) {
        int qt = 2 * p + j;
        if (kti > qt) continue;  // compile-time resolved (all loops unrolled)
        f32x4 sacc[4];
#pragma unroll
        for (int jj = 0; jj < 4; jj++) sacc[jj] = (f32x4){0.f, 0.f, 0.f, 0.f};
#pragma unroll
        for (int ks = 0; ks < 2; ks++)
#pragma unroll
          for (int jj = 0; jj < 4; jj++) {
            bf16x8 bB = ldfrag(kt + (jj * 16 + fr) * 72 + ks * 32 + fq * 8);
            sacc[jj] = __builtin_amdgcn_mfma_f32_16x16x32_bf16(
                rA[j][ks], bB, sacc[jj], 0, 0, 0);
          }
#pragma unroll
        for (int jj = 0; jj < 4; jj++) {
          int kcol = kti * 64 + jj * 16 + fr;
          float ek = ekS[kcol];
#pragma unroll
          for (int rr = 0; rr < 4; rr++) {
            int qrow = qt * 64 + ql0 + rr;
            float vsc;
            if (kcol < qrow)
              vsc = sacc[jj][rr] * eqc[j][rr] * ek;
            else if (kcol == qrow)
              vsc = diagS[qrow];
            else
              vsc = 0.f;
            pt[(ql0 + rr) * 72 + jj * 16 + fr] = f2b(vsc);
          }
        }
        __syncthreads();
#pragma unroll
        for (int ks = 0; ks < 2; ks++) {
          bf16x8 pA = ldfrag(pt + (w * 16 + fr) * 72 + ks * 32 + fq * 8);
#pragma unroll
          for (int jm = 0; jm < 4; jm++) {
            bf16x8 vB = ldfrag(vt + (jm * 16 + fr) * 72 + ks * 32 + fq * 8);
            acc[j][jm] = __builtin_amdgcn_mfma_f32_16x16x32_bf16(
                pA, vB, acc[j][jm], 0, 0, 0);
          }
        }
        __syncthreads();  // pt consumed before next j/kti overwrites
      }
    }
    // write out both qt of the pair
#pragma unroll
    for (int j = 0; j < 2; j++) {
      int qg0 = (2 * p + j) * 64 + ql0;
#pragma unroll
      for (int jm = 0; jm < 4; jm++)
#pragma unroll
        for (int rr = 0; rr < 4; rr++)
          y[rowbase + (size_t)(qg0 + rr) * CC + jm * 16 + fr] = acc[j][jm][rr];
    }
  }
}

// ---------------------------------------------------------------------------
// 10. LayerNorm over C -> bf16 (float4 loads/stores)
// ---------------------------------------------------------------------------
__global__ __launch_bounds__(256) void ln_kernel(const float* __restrict__ y,
                                                 const float* __restrict__ g,
                                                 const float* __restrict__ bta,
                                                 u16* __restrict__ out) {
  __shared__ float red[8];
  int bt = blockIdx.x;
  int tid = threadIdx.x;
  float4 v = *(const float4*)(y + (size_t)bt * 1024 + tid * 4);
  float s = v.x + v.y + v.z + v.w;
#pragma unroll
  for (int off = 32; off > 0; off >>= 1) s += __shfl_down(s, off);
  if ((tid & 63) == 0) red[tid >> 6] = s;
  __syncthreads();
  if (tid == 0) red[4] = red[0] + red[1] + red[2] + red[3];
  __syncthreads();
  float mu = red[4] * (1.f / 1024.f);
  float d0 = v.x - mu, d1 = v.y - mu, d2 = v.z - mu, d3 = v.w - mu;
  float s2 = d0 * d0 + d1 * d1 + d2 * d2 + d3 * d3;
#pragma unroll
  for (int off = 32; off > 0; off >>= 1) s2 += __shfl_down(s2, off);
  __syncthreads();
  if ((tid & 63) == 0) red[tid >> 6] = s2;
  __syncthreads();
  if (tid == 0) red[5] = red[0] + red[1] + red[2] + red[3];
  __syncthreads();
  float var = red[5] * (1.f / 1024.f);
  float rstd = rsqrtf(var + 1e-5f);
  float4 g4 = *(const float4*)(g + tid * 4);
  float4 b4 = *(const float4*)(bta + tid * 4);
  u16x4 o;
  o.x = f2b(d0 * rstd * g4.x + b4.x);
  o.y = f2b(d1 * rstd * g4.y + b4.y);
  o.z = f2b(d2 * rstd * g4.z + b4.z);
  o.w = f2b(d3 * rstd * g4.w + b4.w);
  *(u16x4*)(out + (size_t)bt * 1024 + tid * 4) = o;
}

// ---------------------------------------------------------------------------
extern "C" void kernel_launch(void* const* d_in, const int* in_sizes, int n_in,
                              void* d_out, int out_size, void* d_ws,
                              size_t ws_size, hipStream_t stream) {
  const float* x = (const float*)d_in[0];
  const float* tmx = (const float*)d_in[1];
  const float* tmw = (const float*)d_in[2];
  const float* tmk = (const float*)d_in[3];
  const float* tmv = (const float*)d_in[4];
  const float* tmr = (const float*)d_in[5];
  const float* maa_w1 = (const float*)d_in[6];
  const float* maa_w2 = (const float*)d_in[7];
  const float* decay_w1 = (const float*)d_in[8];
  const float* decay_w2 = (const float*)d_in[9];
  const float* time_decay = (const float*)d_in[10];
  const float* faaaa = (const float*)d_in[11];
  const float* Wr = (const float*)d_in[12];
  const float* Wk = (const float*)d_in[13];
  const float* Wv = (const float*)d_in[14];
  const float* Wo = (const float*)d_in[15];
  const float* lng = (const float*)d_in[16];
  const float* lnb = (const float*)d_in[17];
  float* out = (float*)d_out;
  float* ws = (float*)d_ws;

  const size_t S = (size_t)BT * CC;  // 8388608

  // f32 region
  float* y_ = ws;                     // attn out
  float* dw2r = ws + S;               // 1024
  float* tdr = dw2r + 1024;           // pad to 1024
  float* wlog = tdr + 1024;           // 131072
  float* cum = wlog + 131072;
  float* excl = cum + 131072;
  float* wsl = excl + 131072;         // pad to 1024
  float* diagG = wsl + 1024;          // 131072
  float* kvb = diagG + 131072;        // 512*4096
  float* stb = kvb + (size_t)512 * 4096;
  float* fend = stb + (size_t)512 * 4096;
  // bf16 region (u16)
  u16* xxxb = (u16*)fend;             // mix out -> maa GEMM in -> vT
  u16* mb = xxxb + S;                 // BT*128
  u16* xkb = mb + (size_t)BT * 128;   // blend out -> gemm_dp in -> ylnb
  u16* xvb = xkb + S;                 // blend out -> gemm_dp in
  u16* xrb = xvb + S;                 // blend out -> gemm_dp in
  u16* xwb = xrb + S;                 // blend out -> decay_mfma in
  u16* rb16 = xwb + S;                // gemm_dp out
  u16* kb16 = rb16 + S;               // gemm_dp out
  u16* Vb = kb16 + S;                 // gemm_dp out
  u16* Wrt = Vb + S;
  u16* Wkt = Wrt + (size_t)1024 * 1024;
  u16* Wvt = Wkt + (size_t)1024 * 1024;
  u16* Wot = Wvt + (size_t)1024 * 1024;
  u16* w1T = Wot + (size_t)1024 * 1024;   // [128][1024]
  u16* w2T = w1T + (size_t)128 * 1024;    // [1024][128]
  u16* d1T = w2T + (size_t)1024 * 128;    // [64][1024]
  u16* dw2rbT = d1T + (size_t)64 * 1024;  // [16][64]
  // aliases (stream-ordered reuse)
  u16* vT = xxxb;   // kvfuse writes, attn reads (after gemm_maa consumed xxxb)
  u16* ylnb = xkb;  // after gemm_dp consumed xkb

  // allow 72 KB dynamic LDS for the deep-pipelined GEMMs (once per process)
  static bool attr_done = false;
  if (!attr_done) {
    hipFuncSetAttribute((const void*)gemm_dp<true, false>,
                        hipFuncAttributeMaxDynamicSharedMemorySize, DP_SMEM_BYTES);
    hipFuncSetAttribute((const void*)gemm_dp<false, true>,
                        hipFuncAttributeMaxDynamicSharedMemorySize, DP_SMEM_BYTES);
    attr_done = true;
  }

  // merged weight prep (cvt_wT + cvt3_T + dw2r in one launch)
  cvt_all<<<dim3(16, 16, 8), 256, 0, stream>>>(
      Wr, Wk, Wv, Wo, Wrt, Wkt, Wvt, Wot, maa_w1, maa_w2, decay_w1, w1T, w2T,
      d1T, decay_w2, time_decay, dw2r, tdr, dw2rbT);
  mix_kernel<<<4096, 256, 0, stream>>>(x, tmx, xxxb);
  gemm_maa<<<dim3(2, 128), 256, 0, stream>>>(xxxb, w1T, mb);
  blend_mfma<<<dim3(16, 128), 256, 0, stream>>>(mb, w2T, x, tmw, tmk, tmv, tmr,
                                                xwb, xkb, xvb, xrb);
  decay_mfma<<<256, 256, 0, stream>>>(xwb, d1T, dw2rbT, tdr, wlog);
  wprep_kernel<<<512, 256, 0, stream>>>(wlog, cum, excl, wsl);
  // fused r/k/v projections: deep-pipelined GEMM v5b (BK=32, 2 blocks/CU)
  gemm_dp<true, false><<<dim3(4, 64, 3), 512, DP_SMEM_BYTES, stream>>>(
      xrb, xkb, xvb, Wrt, Wkt, Wvt, nullptr, rb16, kb16, Vb);
  // fused transpose + diag + kv (vectorized v2)
  kvfuse_kernel<<<512, 256, 0, stream>>>(Vb, kb16, rb16, faaaa, cum, wsl, vT,
                                         diagG, kvb);
  scan_kernel<<<256, 256, 0, stream>>>(kvb, wsl, stb);
  attn_mfma<<<512, 256, 0, stream>>>(rb16, kb16, vT, stb, cum, excl, diagG, y_);
  ln_kernel<<<BT, 256, 0, stream>>>(y_, lng, lnb, ylnb);
  // output projection: same deep-pipelined GEMM, f32 out
  gemm_dp<false, true><<<dim3(4, 64, 1), 512, DP_SMEM_BYTES, stream>>>(
      ylnb, nullptr, nullptr, Wot, nullptr, nullptr, out, nullptr, nullptr,
      nullptr);
}